// Round 1
// baseline (1330.345 us; speedup 1.0000x reference)
//
#include <hip/hip_runtime.h>
#include <cstdint>
#include <cstddef>

#define EPSV 1e-5f

typedef short bf16x8 __attribute__((ext_vector_type(8)));
typedef float f32x4 __attribute__((ext_vector_type(4)));

__device__ __forceinline__ short f2bf(float f) {
    union { float f; uint32_t u; } x; x.f = f;
    uint32_t r = (x.u + 0x7fffu + ((x.u >> 16) & 1u)) >> 16;
    return (short)r;
}

// ---------------- zero init ----------------
__global__ void k_zero(float4* p, int n4) {
    int i = blockIdx.x * blockDim.x + threadIdx.x;
    int stride = gridDim.x * blockDim.x;
    for (; i < n4; i += stride) p[i] = float4{0.f, 0.f, 0.f, 0.f};
}

// ---------------- weight conversion: branch main conv weights, j-major reorder ----------------
// Abf[o][j*2048 + c] = w[o][c][j]   (j = ky*k+kx)
__global__ void k_convw(const float* w1, const float* w2, const float* w3, const float* w4,
                        short* A1, short* A2, short* A3, short* A4) {
    int br = blockIdx.y;
    const float* src = br == 0 ? w1 : br == 1 ? w2 : br == 2 ? w3 : w4;
    short* dst = br == 0 ? A1 : br == 1 ? A2 : br == 2 ? A3 : A4;
    int J = (br == 0) ? 1 : 9;
    int total = 256 * 2048 * J;
    int i = blockIdx.x * 256 + threadIdx.x;
    if (i >= total) return;
    int c = i & 2047;
    int r = i >> 11;          // o*J + jj
    int jj = r % J, o = r / J;
    dst[i] = f2bf(src[((size_t)o * 2048 + c) * J + jj]);
}

// ---------------- offset/mod conv weights -> concatenated 128x(9*2048), j-major ----------------
__global__ void k_convoff(const float* woff1, const float* wm1, const float* woff2, const float* wm2,
                          const float* woff3, const float* wm3, const float* woff4, const float* wm4,
                          short* Aoff) {
    int i = blockIdx.x * 256 + threadIdx.x;   // 128*18432
    if (i >= 128 * 18432) return;
    int ch = i / 18432;
    int r = i % 18432;
    int jj = r >> 11, c = r & 2047;
    float v = 0.f;
    if (ch < 2)        v = woff1[((size_t)ch * 2048 + c) * 9 + jj];
    else if (ch == 2)  v = wm1[(size_t)c * 9 + jj];
    else if (ch < 21)  v = woff2[((size_t)(ch - 3) * 2048 + c) * 9 + jj];
    else if (ch < 30)  v = wm2[((size_t)(ch - 21) * 2048 + c) * 9 + jj];
    else if (ch < 48)  v = woff3[((size_t)(ch - 30) * 2048 + c) * 9 + jj];
    else if (ch < 57)  v = wm3[((size_t)(ch - 48) * 2048 + c) * 9 + jj];
    else if (ch < 75)  v = woff4[((size_t)(ch - 57) * 2048 + c) * 9 + jj];
    else if (ch < 84)  v = wm4[((size_t)(ch - 75) * 2048 + c) * 9 + jj];
    Aoff[i] = f2bf(v);
}

__global__ void k_afuse(const float* wfuse, short* Af) {
    int i = blockIdx.x * 256 + threadIdx.x;
    if (i < 256 * 1280) Af[i] = f2bf(wfuse[i]);
}

// ---------------- shift table for the 3x3 pad-1 offset conv ----------------
__global__ void k_shtab(int* sh) {
    int i = blockIdx.x * 256 + threadIdx.x;   // 9*2048
    if (i >= 9 * 2048) return;
    int j = i >> 11, p = i & 2047;
    int hw = p & 1023, h = hw >> 5, w = hw & 31;
    int y = h + j / 3 - 1, x = w + j % 3 - 1;
    sh[i] = (y >= 0 && y < 32 && x >= 0 && x < 32) ? (y * 32 + x) : -1;
}

// ---------------- deform sampling tables ----------------
// entries: br0 j0 [0,2048) | br1 [2048,20480) | br2 [20480,38912) | br3 [38912,57344)
__global__ void k_sample(const float* OM, int* dtabi) {
    int i = blockIdx.x * 256 + threadIdx.x;
    if (i >= 57344) return;
    int br, j, p;
    if (i < 2048) { br = 0; j = 0; p = i; }
    else { int r = i - 2048; br = 1 + r / 18432; r %= 18432; j = r >> 11; p = r & 2047; }
    const int dil_[4] = {1, 6, 12, 18};
    const int pad_[4] = {0, 6, 12, 18};
    const int cho_[4] = {0, 3, 30, 57};
    const int chm_[4] = {2, 21, 48, 75};
    const int tbo_[4] = {0, 2048, 20480, 38912};
    int J = br ? 9 : 1;
    int dil = dil_[br], pad = pad_[br];
    int hw = p & 1023, h = hw >> 5, w = hw & 31;
    float offy = OM[(size_t)(cho_[br] + j) * 2048 + p];
    float offx = OM[(size_t)(cho_[br] + J + j) * 2048 + p];
    float mz   = OM[(size_t)(chm_[br] + j) * 2048 + p];
    float m = 1.f / (1.f + expf(-mz));
    int ky = j / 3, kx = j - ky * 3;
    float fh = (float)(h + ky * dil) + offy;
    float fw = (float)(w + kx * dil) + offx;
    int limi = 31 + 2 * pad;
    float lim = (float)limi;
    fh = fminf(fmaxf(fh, 0.f), lim);
    fw = fminf(fmaxf(fw, 0.f), lim);
    float y0f = floorf(fh), x0f = floorf(fw);
    float wy = fh - y0f, wx = fw - x0f;
    int y0 = (int)y0f, x0 = (int)x0f;
    int y1 = min(y0 + 1, limi), x1 = min(x0 + 1, limi);
    int4 ii; float4 ww;
    {
        int yo = y0 - pad, xo = x0 - pad;
        bool v = ((unsigned)yo < 32u) && ((unsigned)xo < 32u);
        ii.x = v ? yo * 32 + xo : 0; ww.x = v ? (1.f - wy) * (1.f - wx) * m : 0.f;
    }
    {
        int yo = y0 - pad, xo = x1 - pad;
        bool v = ((unsigned)yo < 32u) && ((unsigned)xo < 32u);
        ii.y = v ? yo * 32 + xo : 0; ww.y = v ? (1.f - wy) * wx * m : 0.f;
    }
    {
        int yo = y1 - pad, xo = x0 - pad;
        bool v = ((unsigned)yo < 32u) && ((unsigned)xo < 32u);
        ii.z = v ? yo * 32 + xo : 0; ww.z = v ? wy * (1.f - wx) * m : 0.f;
    }
    {
        int yo = y1 - pad, xo = x1 - pad;
        bool v = ((unsigned)yo < 32u) && ((unsigned)xo < 32u);
        ii.w = v ? yo * 32 + xo : 0; ww.w = v ? wy * wx * m : 0.f;
    }
    int ent = tbo_[br] + j * 2048 + p;
    ((int4*)dtabi)[(size_t)ent * 2] = ii;
    ((float4*)dtabi)[(size_t)ent * 2 + 1] = ww;
}

// ---------------- MFMA GEMM, 128x128 tile, BK=32, 16x16x32 bf16 ----------------
// MODE 0: B from dense bf16 [2048][K] (fuse GEMM)
// MODE 1: B[k=(j,c)][p] = shifted x (offset/mod conv im2col)
// MODE 2: B[k=(j,c)][p] = 4-tap bilinear gather * modulation (deform conv)
template <int MODE>
__global__ __launch_bounds__(256) void k_gemm(
    const short* __restrict__ A, const short* __restrict__ Bp,
    const float* __restrict__ X, const int* __restrict__ tab,
    float* __restrict__ C, int K, int kchunk)
{
    __shared__ __align__(16) short At[128][40];
    __shared__ __align__(16) short Bt[128][40];
    int t = threadIdx.x;
    int nbase = blockIdx.x * 128;
    int mbase = blockIdx.y * 128;
    int kbeg = blockIdx.z * kchunk;
    int kend = kbeg + kchunk;

    f32x4 acc[4][4] = {};

    int p = t & 127;
    int cg = t >> 7;
    int pg = nbase + p;
    const float* xb = nullptr;
    if (MODE != 0) xb = X + (size_t)(pg >> 10) * (2048 * 1024);

    int lane = t & 63, wv = t >> 6;
    int mq = (wv >> 1) * 64, nq = (wv & 1) * 64;
    int lm = lane & 15, quad = lane >> 4;

    for (int k0 = kbeg; k0 < kend; k0 += 32) {
        // stage A tile (rows = out channels)
        {
            int row = t >> 2, seg = t & 3;
            *(uint4*)&At[row][seg * 8] = *(const uint4*)(A + (size_t)(mbase + row) * K + k0 + seg * 8);
            row += 64;
            *(uint4*)&At[row][seg * 8] = *(const uint4*)(A + (size_t)(mbase + row) * K + k0 + seg * 8);
        }
        // stage B tile (rows = positions, transposed [n][k])
        if (MODE == 0) {
            int row = t >> 2, seg = t & 3;
            *(uint4*)&Bt[row][seg * 8] = *(const uint4*)(Bp + (size_t)(nbase + row) * K + k0 + seg * 8);
            row += 64;
            *(uint4*)&Bt[row][seg * 8] = *(const uint4*)(Bp + (size_t)(nbase + row) * K + k0 + seg * 8);
        } else if (MODE == 1) {
            int j = k0 >> 11, c0 = k0 & 2047;
            int sidx = tab[j * 2048 + pg];
            const float* basep = xb + (size_t)c0 * 1024;
            #pragma unroll
            for (int rep = 0; rep < 2; rep++) {
                int cl = rep * 16 + cg * 8;
                bf16x8 pk;
                const float* bc = basep + (size_t)cl * 1024;
                #pragma unroll
                for (int cc = 0; cc < 8; cc++) {
                    float v = (sidx >= 0) ? bc[(size_t)cc * 1024 + sidx] : 0.f;
                    pk[cc] = f2bf(v);
                }
                *(bf16x8*)&Bt[p][cl] = pk;
            }
        } else {
            int j = k0 >> 11, c0 = k0 & 2047;
            const int4* te = (const int4*)tab + ((size_t)j * 2048 + pg) * 2;
            int4 ii = te[0];
            float4 ww = *(const float4*)(te + 1);
            const float* basep = xb + (size_t)c0 * 1024;
            #pragma unroll
            for (int rep = 0; rep < 2; rep++) {
                int cl = rep * 16 + cg * 8;
                bf16x8 pk;
                const float* bc = basep + (size_t)cl * 1024;
                #pragma unroll
                for (int cc = 0; cc < 8; cc++) {
                    const float* b4 = bc + (size_t)cc * 1024;
                    float v = ww.x * b4[ii.x] + ww.y * b4[ii.y]
                            + ww.z * b4[ii.z] + ww.w * b4[ii.w];
                    pk[cc] = f2bf(v);
                }
                *(bf16x8*)&Bt[p][cl] = pk;
            }
        }
        __syncthreads();
        bf16x8 af[4], bfr[4];
        #pragma unroll
        for (int f = 0; f < 4; f++) {
            af[f]  = *(const bf16x8*)&At[mq + f * 16 + lm][quad * 8];
            bfr[f] = *(const bf16x8*)&Bt[nq + f * 16 + lm][quad * 8];
        }
        #pragma unroll
        for (int fm = 0; fm < 4; fm++)
            #pragma unroll
            for (int fn = 0; fn < 4; fn++)
                acc[fm][fn] = __builtin_amdgcn_mfma_f32_16x16x32_bf16(af[fm], bfr[fn], acc[fm][fn], 0, 0, 0);
        __syncthreads();
    }
    // epilogue: C/D layout col=lane&15, row=quad*4+reg
    #pragma unroll
    for (int fm = 0; fm < 4; fm++) {
        int row0 = mbase + mq + fm * 16 + quad * 4;
        #pragma unroll
        for (int fn = 0; fn < 4; fn++) {
            int col = nbase + nq + fn * 16 + lm;
            #pragma unroll
            for (int r = 0; r < 4; r++)
                atomicAdd(&C[(size_t)(row0 + r) * 2048 + col], acc[fm][fn][r]);
        }
    }
}

// ---------------- BN stats: per-channel scale/shift over 2048 samples ----------------
__global__ void k_bnstats(const float* Y0, const float* Y1, const float* Y2, const float* Y3,
                          const float* g0, const float* g1, const float* g2, const float* g3,
                          const float* b0, const float* b1, const float* b2, const float* b3,
                          float* S) {
    int br = blockIdx.y;
    const float* Y = br == 0 ? Y0 : br == 1 ? Y1 : br == 2 ? Y2 : Y3;
    const float* g = br == 0 ? g0 : br == 1 ? g1 : br == 2 ? g2 : g3;
    const float* b = br == 0 ? b0 : br == 1 ? b1 : br == 2 ? b2 : b3;
    float* so = S + (size_t)br * 512;
    int o = blockIdx.x, t = threadIdx.x;
    const float* row = Y + (size_t)o * 2048;
    float s = 0.f, ss = 0.f;
    for (int i = t; i < 2048; i += 256) { float v = row[i]; s += v; ss += v * v; }
    #pragma unroll
    for (int off = 32; off; off >>= 1) { s += __shfl_down(s, off); ss += __shfl_down(ss, off); }
    __shared__ float ls[4], lss[4];
    int wv = t >> 6;
    if ((t & 63) == 0) { ls[wv] = s; lss[wv] = ss; }
    __syncthreads();
    if (t == 0) {
        s = ls[0] + ls[1] + ls[2] + ls[3];
        ss = lss[0] + lss[1] + lss[2] + lss[3];
        float mu = s * (1.f / 2048.f);
        float var = ss * (1.f / 2048.f) - mu * mu;
        float sc = g[o] * rsqrtf(var + EPSV);
        so[o] = sc;
        so[256 + o] = b[o] - mu * sc;
    }
}

// ---------------- global average pool ----------------
__global__ void k_gap(const float* X, float* gap) {
    int bc = blockIdx.x;       // 4096 = [b][c]
    const float* row = X + (size_t)bc * 1024;
    int t = threadIdx.x;
    float s = row[t] + row[t + 256] + row[t + 512] + row[t + 768];
    #pragma unroll
    for (int off = 32; off; off >>= 1) s += __shfl_down(s, off);
    __shared__ float ls[4];
    if ((t & 63) == 0) ls[t >> 6] = s;
    __syncthreads();
    if (t == 0) gap[bc] = (ls[0] + ls[1] + ls[2] + ls[3]) * (1.f / 1024.f);
}

// ---------------- pool 1x1 conv + BN over batch (2) + relu ----------------
__global__ void k_pool(const float* gap, const float* wpool, const float* gp, const float* bp,
                       float* pfin) {
    int o = blockIdx.x, t = threadIdx.x;
    float s0 = 0.f, s1 = 0.f;
    const float* wr = wpool + (size_t)o * 2048;
    for (int c = t; c < 2048; c += 256) {
        float wv = wr[c];
        s0 += wv * gap[c];
        s1 += wv * gap[2048 + c];
    }
    #pragma unroll
    for (int off = 32; off; off >>= 1) { s0 += __shfl_down(s0, off); s1 += __shfl_down(s1, off); }
    __shared__ float l0[4], l1[4];
    int wv_ = t >> 6;
    if ((t & 63) == 0) { l0[wv_] = s0; l1[wv_] = s1; }
    __syncthreads();
    if (t == 0) {
        float p0 = l0[0] + l0[1] + l0[2] + l0[3];
        float p1 = l1[0] + l1[1] + l1[2] + l1[3];
        float mu = 0.5f * (p0 + p1);
        float d0 = p0 - mu, d1 = p1 - mu;
        float var = 0.5f * (d0 * d0 + d1 * d1);
        float r = rsqrtf(var + EPSV);
        pfin[o]       = fmaxf(d0 * r * gp[o] + bp[o], 0.f);
        pfin[256 + o] = fmaxf(d1 * r * gp[o] + bp[o], 0.f);
    }
}

// ---------------- build fuse-GEMM B matrix: [2048 positions][1280] bf16 ----------------
__global__ void k_xcat(const float* ypre, const float* S, const float* pfin, short* xcat) {
    int pidx = blockIdx.x;
    int b = pidx >> 10;
    int t = threadIdx.x;
    for (int c = t; c < 1280; c += 256) {
        float v;
        if (c < 1024) {
            int br = c >> 8, cc = c & 255;
            float sc = S[(size_t)br * 512 + cc], sh = S[(size_t)br * 512 + 256 + cc];
            v = fmaxf(ypre[((size_t)br * 256 + cc) * 2048 + pidx] * sc + sh, 0.f);
        } else {
            v = pfin[b * 256 + (c - 1024)];
        }
        xcat[(size_t)pidx * 1280 + c] = f2bf(v);
    }
}

// ---------------- final BN + relu + layout to [B][O][HW] ----------------
__global__ void k_final(const float* outpre, const float* S, float* dout) {
    int i = blockIdx.x * 256 + threadIdx.x;    // 524288
    int hw = i & 1023, o = (i >> 10) & 255, b = i >> 18;
    float v = outpre[(size_t)o * 2048 + b * 1024 + hw] * S[o] + S[256 + o];
    dout[i] = fmaxf(v, 0.f);
}

extern "C" void kernel_launch(void* const* d_in, const int* in_sizes, int n_in,
                              void* d_out, int out_size, void* d_ws, size_t ws_size,
                              hipStream_t stream) {
    const float* x     = (const float*)d_in[0];
    const float* woff1 = (const float*)d_in[1];
    const float* wm1   = (const float*)d_in[2];
    const float* w1    = (const float*)d_in[3];
    const float* g1    = (const float*)d_in[4];
    const float* b1    = (const float*)d_in[5];
    const float* woff2 = (const float*)d_in[6];
    const float* wm2   = (const float*)d_in[7];
    const float* w2    = (const float*)d_in[8];
    const float* g2    = (const float*)d_in[9];
    const float* b2    = (const float*)d_in[10];
    const float* woff3 = (const float*)d_in[11];
    const float* wm3   = (const float*)d_in[12];
    const float* w3    = (const float*)d_in[13];
    const float* g3    = (const float*)d_in[14];
    const float* b3    = (const float*)d_in[15];
    const float* woff4 = (const float*)d_in[16];
    const float* wm4   = (const float*)d_in[17];
    const float* w4    = (const float*)d_in[18];
    const float* g4    = (const float*)d_in[19];
    const float* b4    = (const float*)d_in[20];
    const float* wpool = (const float*)d_in[21];
    const float* gp    = (const float*)d_in[22];
    const float* bp    = (const float*)d_in[23];
    const float* wfuse = (const float*)d_in[24];
    const float* gf    = (const float*)d_in[25];
    const float* bf    = (const float*)d_in[26];

    char* ws = (char*)d_ws;
    size_t off = 0;
    auto alloc = [&](size_t bytes) {
        off = (off + 255) & ~(size_t)255;
        size_t o = off; off += bytes; return o;
    };
    // zero-init region must be contiguous: offmod | ypre | outpre
    size_t off_offmod = alloc(128 * 2048 * 4);
    size_t off_ypre   = alloc((size_t)4 * 256 * 2048 * 4);
    size_t off_outpre = alloc(256 * 2048 * 4);
    size_t off_A1     = alloc((size_t)256 * 2048 * 2);
    size_t off_A2     = alloc((size_t)256 * 18432 * 2);
    size_t off_A3     = alloc((size_t)256 * 18432 * 2);
    size_t off_A4     = alloc((size_t)256 * 18432 * 2);
    size_t off_Aoff   = alloc((size_t)128 * 18432 * 2);
    size_t off_Afuse  = alloc((size_t)256 * 1280 * 2);
    size_t off_xcat   = alloc((size_t)2048 * 1280 * 2);
    size_t off_shtab  = alloc((size_t)9 * 2048 * 4);
    size_t off_dtab   = alloc((size_t)57344 * 32);
    size_t off_scsh   = alloc((size_t)4 * 512 * 4);
    size_t off_scshf  = alloc((size_t)512 * 4);
    size_t off_gap    = alloc((size_t)4096 * 4);
    size_t off_pfin   = alloc((size_t)512 * 4);
    (void)ws_size; (void)in_sizes; (void)n_in; (void)out_size;

    float* offmod = (float*)(ws + off_offmod);
    float* ypre   = (float*)(ws + off_ypre);
    float* outpre = (float*)(ws + off_outpre);
    short* A1     = (short*)(ws + off_A1);
    short* A2     = (short*)(ws + off_A2);
    short* A3     = (short*)(ws + off_A3);
    short* A4     = (short*)(ws + off_A4);
    short* Aoff   = (short*)(ws + off_Aoff);
    short* Afuse  = (short*)(ws + off_Afuse);
    short* xcat   = (short*)(ws + off_xcat);
    int*   shtab  = (int*)(ws + off_shtab);
    int*   dtab   = (int*)(ws + off_dtab);
    float* scsh   = (float*)(ws + off_scsh);
    float* scshf  = (float*)(ws + off_scshf);
    float* gapb   = (float*)(ws + off_gap);
    float* pfin   = (float*)(ws + off_pfin);

    // 1. zero accumulators (offmod + ypre + outpre contiguous: 2,883,584 floats)
    k_zero<<<2048, 256, 0, stream>>>((float4*)(ws + off_offmod), 720896);
    // 2. weight conversions
    k_convw<<<dim3(18432, 4), 256, 0, stream>>>(w1, w2, w3, w4, A1, A2, A3, A4);
    k_convoff<<<9216, 256, 0, stream>>>(woff1, wm1, woff2, wm2, woff3, wm3, woff4, wm4, Aoff);
    k_afuse<<<1280, 256, 0, stream>>>(wfuse, Afuse);
    k_shtab<<<72, 256, 0, stream>>>(shtab);
    // 3. offset/mod conv GEMM: M=128(84 used), K=9*2048, N=2048, ksplit=8
    k_gemm<1><<<dim3(16, 1, 8), 256, 0, stream>>>(Aoff, nullptr, x, shtab, offmod, 18432, 2304);
    // 4. sampling tables
    k_sample<<<224, 256, 0, stream>>>(offmod, dtab);
    // 5. deform conv GEMMs
    k_gemm<2><<<dim3(16, 2, 2), 256, 0, stream>>>(A1, nullptr, x, dtab, ypre, 2048, 1024);
    k_gemm<2><<<dim3(16, 2, 8), 256, 0, stream>>>(A2, nullptr, x, dtab + (size_t)2048 * 8,
                                                  ypre + (size_t)1 * 524288, 18432, 2304);
    k_gemm<2><<<dim3(16, 2, 8), 256, 0, stream>>>(A3, nullptr, x, dtab + (size_t)20480 * 8,
                                                  ypre + (size_t)2 * 524288, 18432, 2304);
    k_gemm<2><<<dim3(16, 2, 8), 256, 0, stream>>>(A4, nullptr, x, dtab + (size_t)38912 * 8,
                                                  ypre + (size_t)3 * 524288, 18432, 2304);
    // 6. branch BN stats
    k_bnstats<<<dim3(256, 4), 256, 0, stream>>>(ypre, ypre + 524288, ypre + 2 * 524288, ypre + 3 * 524288,
                                                g1, g2, g3, g4, b1, b2, b3, b4, scsh);
    // 7. pool branch
    k_gap<<<4096, 256, 0, stream>>>(x, gapb);
    k_pool<<<256, 256, 0, stream>>>(gapb, wpool, gp, bp, pfin);
    // 8. concat (BN+relu applied) as bf16 [2048][1280]
    k_xcat<<<2048, 256, 0, stream>>>(ypre, scsh, pfin, xcat);
    // 9. fuse GEMM: M=256, K=1280, N=2048, ksplit=4
    k_gemm<0><<<dim3(16, 2, 4), 256, 0, stream>>>(Afuse, xcat, nullptr, nullptr, outpre, 1280, 320);
    // 10. final BN stats + apply
    k_bnstats<<<dim3(256, 1), 256, 0, stream>>>(outpre, outpre, outpre, outpre,
                                                gf, gf, gf, gf, bf, bf, bf, bf, scshf);
    k_final<<<2048, 256, 0, stream>>>(outpre, scshf, (float*)d_out);
}

// Round 2
// 482.376 us; speedup vs baseline: 2.7579x; 2.7579x over previous
//
#include <hip/hip_runtime.h>
#include <cstdint>
#include <cstddef>

#define EPSV 1e-5f

typedef short bf16x8 __attribute__((ext_vector_type(8)));
typedef float f32x4 __attribute__((ext_vector_type(4)));

__device__ __forceinline__ short f2bf(float f) {
    union { float f; uint32_t u; } x; x.f = f;
    uint32_t r = (x.u + 0x7fffu + ((x.u >> 16) & 1u)) >> 16;
    return (short)r;
}
__device__ __forceinline__ float lo16(uint32_t u) {
    union { uint32_t u; float f; } x; x.u = u << 16; return x.f;
}
__device__ __forceinline__ float hi16(uint32_t u) {
    union { uint32_t u; float f; } x; x.u = u & 0xffff0000u; return x.f;
}

// ---------------- zero init ----------------
__global__ void k_zero(float4* p, int n4) {
    int i = blockIdx.x * blockDim.x + threadIdx.x;
    int stride = gridDim.x * blockDim.x;
    for (; i < n4; i += stride) p[i] = float4{0.f, 0.f, 0.f, 0.f};
}

// ---------------- transpose x: [B][C][HW] f32 -> xT [B][HW][C] bf16 ----------------
__global__ void k_xpose(const float* __restrict__ x, short* __restrict__ xT) {
    int hw0 = blockIdx.x * 64, c0 = blockIdx.y * 64, b = blockIdx.z;
    __shared__ short tile[64][72];
    int t = threadIdx.x;
    const float* xb = x + (size_t)b * 2048 * 1024;
    int hwi = t & 63, cr = t >> 6;
    #pragma unroll
    for (int r = 0; r < 16; r++) {
        int cl = cr + r * 4;
        tile[hwi][cl] = f2bf(xb[(size_t)(c0 + cl) * 1024 + hw0 + hwi]);
    }
    __syncthreads();
    short* xTb = xT + (size_t)b * 1024 * 2048;
    int ci = t & 63, hr = t >> 6;
    #pragma unroll
    for (int r = 0; r < 16; r++) {
        int hwr = hr + r * 4;
        xTb[(size_t)(hw0 + hwr) * 2048 + c0 + ci] = tile[hwr][ci];
    }
}

// ---------------- weight conversion: branch main conv weights, j-major reorder ----------------
__global__ void k_convw(const float* w1, const float* w2, const float* w3, const float* w4,
                        short* A1, short* A2, short* A3, short* A4) {
    int br = blockIdx.y;
    const float* src = br == 0 ? w1 : br == 1 ? w2 : br == 2 ? w3 : w4;
    short* dst = br == 0 ? A1 : br == 1 ? A2 : br == 2 ? A3 : A4;
    int J = (br == 0) ? 1 : 9;
    int total = 256 * 2048 * J;
    int i = blockIdx.x * 256 + threadIdx.x;
    if (i >= total) return;
    int c = i & 2047;
    int r = i >> 11;          // o*J + jj
    int jj = r % J, o = r / J;
    dst[i] = f2bf(src[((size_t)o * 2048 + c) * J + jj]);
}

// ---------------- offset/mod conv weights -> concatenated 128x(9*2048), j-major ----------------
__global__ void k_convoff(const float* woff1, const float* wm1, const float* woff2, const float* wm2,
                          const float* woff3, const float* wm3, const float* woff4, const float* wm4,
                          short* Aoff) {
    int i = blockIdx.x * 256 + threadIdx.x;   // 128*18432
    if (i >= 128 * 18432) return;
    int ch = i / 18432;
    int r = i % 18432;
    int jj = r >> 11, c = r & 2047;
    float v = 0.f;
    if (ch < 2)        v = woff1[((size_t)ch * 2048 + c) * 9 + jj];
    else if (ch == 2)  v = wm1[(size_t)c * 9 + jj];
    else if (ch < 21)  v = woff2[((size_t)(ch - 3) * 2048 + c) * 9 + jj];
    else if (ch < 30)  v = wm2[((size_t)(ch - 21) * 2048 + c) * 9 + jj];
    else if (ch < 48)  v = woff3[((size_t)(ch - 30) * 2048 + c) * 9 + jj];
    else if (ch < 57)  v = wm3[((size_t)(ch - 48) * 2048 + c) * 9 + jj];
    else if (ch < 75)  v = woff4[((size_t)(ch - 57) * 2048 + c) * 9 + jj];
    else if (ch < 84)  v = wm4[((size_t)(ch - 75) * 2048 + c) * 9 + jj];
    Aoff[i] = f2bf(v);
}

__global__ void k_afuse(const float* wfuse, short* Af) {
    int i = blockIdx.x * 256 + threadIdx.x;
    if (i < 256 * 1280) Af[i] = f2bf(wfuse[i]);
}

// ---------------- synthetic 1-tap table for the 3x3 pad-1 offset conv ----------------
__global__ void k_shtab(int* dtab0) {
    int i = blockIdx.x * 256 + threadIdx.x;   // 9*2048
    if (i >= 9 * 2048) return;
    int j = i >> 11, p = i & 2047;
    int hw = p & 1023, h = hw >> 5, w = hw & 31;
    int y = h + j / 3 - 1, xx = w + j % 3 - 1;
    bool v = (y >= 0 && y < 32 && xx >= 0 && xx < 32);
    int4 ii = {v ? y * 32 + xx : 0, 0, 0, 0};
    float4 ww = {v ? 1.f : 0.f, 0.f, 0.f, 0.f};
    ((int4*)dtab0)[(size_t)i * 2] = ii;
    ((float4*)dtab0)[(size_t)i * 2 + 1] = ww;
}

// ---------------- deform sampling tables ----------------
// entries: br0 j0 [0,2048) | br1 [2048,20480) | br2 [20480,38912) | br3 [38912,57344)
__global__ void k_sample(const float* OM, int* dtabi) {
    int i = blockIdx.x * 256 + threadIdx.x;
    if (i >= 57344) return;
    int br, j, p;
    if (i < 2048) { br = 0; j = 0; p = i; }
    else { int r = i - 2048; br = 1 + r / 18432; r %= 18432; j = r >> 11; p = r & 2047; }
    const int dil_[4] = {1, 6, 12, 18};
    const int pad_[4] = {0, 6, 12, 18};
    const int cho_[4] = {0, 3, 30, 57};
    const int chm_[4] = {2, 21, 48, 75};
    const int tbo_[4] = {0, 2048, 20480, 38912};
    int J = br ? 9 : 1;
    int dil = dil_[br], pad = pad_[br];
    int hw = p & 1023, h = hw >> 5, w = hw & 31;
    float offy = OM[(size_t)(cho_[br] + j) * 2048 + p];
    float offx = OM[(size_t)(cho_[br] + J + j) * 2048 + p];
    float mz   = OM[(size_t)(chm_[br] + j) * 2048 + p];
    float m = 1.f / (1.f + expf(-mz));
    int ky = j / 3, kx = j - ky * 3;
    float fh = (float)(h + ky * dil) + offy;
    float fw = (float)(w + kx * dil) + offx;
    int limi = 31 + 2 * pad;
    float lim = (float)limi;
    fh = fminf(fmaxf(fh, 0.f), lim);
    fw = fminf(fmaxf(fw, 0.f), lim);
    float y0f = floorf(fh), x0f = floorf(fw);
    float wy = fh - y0f, wx = fw - x0f;
    int y0 = (int)y0f, x0 = (int)x0f;
    int y1 = min(y0 + 1, limi), x1 = min(x0 + 1, limi);
    int4 ii; float4 ww;
    {
        int yo = y0 - pad, xo = x0 - pad;
        bool v = ((unsigned)yo < 32u) && ((unsigned)xo < 32u);
        ii.x = v ? yo * 32 + xo : 0; ww.x = v ? (1.f - wy) * (1.f - wx) * m : 0.f;
    }
    {
        int yo = y0 - pad, xo = x1 - pad;
        bool v = ((unsigned)yo < 32u) && ((unsigned)xo < 32u);
        ii.y = v ? yo * 32 + xo : 0; ww.y = v ? (1.f - wy) * wx * m : 0.f;
    }
    {
        int yo = y1 - pad, xo = x0 - pad;
        bool v = ((unsigned)yo < 32u) && ((unsigned)xo < 32u);
        ii.z = v ? yo * 32 + xo : 0; ww.z = v ? wy * (1.f - wx) * m : 0.f;
    }
    {
        int yo = y1 - pad, xo = x1 - pad;
        bool v = ((unsigned)yo < 32u) && ((unsigned)xo < 32u);
        ii.w = v ? yo * 32 + xo : 0; ww.w = v ? wy * wx * m : 0.f;
    }
    int ent = tbo_[br] + j * 2048 + p;
    ((int4*)dtabi)[(size_t)ent * 2] = ii;
    ((float4*)dtabi)[(size_t)ent * 2 + 1] = ww;
}

// ---------------- gather GEMM body: 128x128 tile, BK=32, 16x16x32 bf16 ----------------
// B[k=(j,c)][p] = sum_{tap} ww[tap] * xT[b][ii[tap]][c], coalesced NHWC bf16 loads.
__device__ __forceinline__ void gemm_gather(
    const short* __restrict__ A, const int* __restrict__ tab,
    const short* __restrict__ xT, float* __restrict__ C,
    int K, int kbeg, int kend, int nbase, int mbase)
{
    __shared__ __align__(16) short At[128][40];
    __shared__ __align__(16) short Bt[128][40];
    int t = threadIdx.x;
    f32x4 acc[4][4] = {};

    int p = t >> 1;                 // position within tile
    int choff = (t & 1) * 16;       // channel half
    int pg = nbase + p;
    int bb = nbase >> 10;           // batch (block-uniform)

    int j = kbeg >> 11;             // kchunk always within one j
    const int4* te = (const int4*)tab + ((size_t)j * 2048 + pg) * 2;
    int4 ii = te[0];
    float4 ww = *(const float4*)(te + 1);
    const short* xbase = xT + (size_t)bb * 1024 * 2048 + choff;
    const short* rp0 = xbase + (size_t)ii.x * 2048;
    const short* rp1 = xbase + (size_t)ii.y * 2048;
    const short* rp2 = xbase + (size_t)ii.z * 2048;
    const short* rp3 = xbase + (size_t)ii.w * 2048;

    int lane = t & 63, wv = t >> 6;
    int mq = (wv >> 1) * 64, nq = (wv & 1) * 64;
    int lm = lane & 15, quad = lane >> 4;

    for (int k0 = kbeg; k0 < kend; k0 += 32) {
        // stage A tile
        {
            int row = t >> 2, seg = t & 3;
            *(uint4*)&At[row][seg * 8] = *(const uint4*)(A + (size_t)(mbase + row) * K + k0 + seg * 8);
            *(uint4*)&At[row + 64][seg * 8] = *(const uint4*)(A + (size_t)(mbase + row + 64) * K + k0 + seg * 8);
        }
        // stage B tile: bilinear gather, 16 channels per thread
        {
            int ck = k0 & 2047;
            float v[16];
            #pragma unroll
            for (int e = 0; e < 16; e++) v[e] = 0.f;
            #define TAP(RP, W) { \
                const uint4* q = (const uint4*)(RP + ck); \
                uint4 u0 = q[0], u1 = q[1]; \
                float w = W; \
                v[0] += w * lo16(u0.x);  v[1] += w * hi16(u0.x); \
                v[2] += w * lo16(u0.y);  v[3] += w * hi16(u0.y); \
                v[4] += w * lo16(u0.z);  v[5] += w * hi16(u0.z); \
                v[6] += w * lo16(u0.w);  v[7] += w * hi16(u0.w); \
                v[8] += w * lo16(u1.x);  v[9] += w * hi16(u1.x); \
                v[10] += w * lo16(u1.y); v[11] += w * hi16(u1.y); \
                v[12] += w * lo16(u1.z); v[13] += w * hi16(u1.z); \
                v[14] += w * lo16(u1.w); v[15] += w * hi16(u1.w); }
            TAP(rp0, ww.x) TAP(rp1, ww.y) TAP(rp2, ww.z) TAP(rp3, ww.w)
            #undef TAP
            bf16x8 pk0, pk1;
            #pragma unroll
            for (int e = 0; e < 8; e++) { pk0[e] = f2bf(v[e]); pk1[e] = f2bf(v[8 + e]); }
            *(bf16x8*)&Bt[p][choff] = pk0;
            *(bf16x8*)&Bt[p][choff + 8] = pk1;
        }
        __syncthreads();
        bf16x8 af[4], bfr[4];
        #pragma unroll
        for (int f = 0; f < 4; f++) {
            af[f]  = *(const bf16x8*)&At[mq + f * 16 + lm][quad * 8];
            bfr[f] = *(const bf16x8*)&Bt[nq + f * 16 + lm][quad * 8];
        }
        #pragma unroll
        for (int fm = 0; fm < 4; fm++)
            #pragma unroll
            for (int fn = 0; fn < 4; fn++)
                acc[fm][fn] = __builtin_amdgcn_mfma_f32_16x16x32_bf16(af[fm], bfr[fn], acc[fm][fn], 0, 0, 0);
        __syncthreads();
    }
    #pragma unroll
    for (int fm = 0; fm < 4; fm++) {
        int row0 = mbase + mq + fm * 16 + quad * 4;
        #pragma unroll
        for (int fn = 0; fn < 4; fn++) {
            int col = nbase + nq + fn * 16 + lm;
            #pragma unroll
            for (int r = 0; r < 4; r++)
                atomicAdd(&C[(size_t)(row0 + r) * 2048 + col], acc[fm][fn][r]);
        }
    }
}

// offset/mod conv GEMM: M=128, K=18432, kchunk=512, grid (16,1,36)
__global__ __launch_bounds__(256) void k_ogemm(const short* __restrict__ Aoff,
                                               const int* __restrict__ dtab0,
                                               const short* __restrict__ xT,
                                               float* __restrict__ offmod) {
    int kbeg = blockIdx.z * 512;
    gemm_gather(Aoff, dtab0, xT, offmod, 18432, kbeg, kbeg + 512, blockIdx.x * 128, 0);
}

// merged 4-branch deform GEMM: kchunk=1024, grid (16,2,56)
__global__ __launch_bounds__(256) void k_dgemm(const short* __restrict__ Aall,
                                               const int* __restrict__ dtab,
                                               const short* __restrict__ xT,
                                               float* __restrict__ ypre) {
    int z = blockIdx.z;
    int br, zz;
    if (z < 2) { br = 0; zz = z; } else { br = 1 + (z - 2) / 18; zz = (z - 2) % 18; }
    const size_t aoffs[4] = {0, (size_t)256 * 2048, (size_t)256 * 2048 + (size_t)256 * 18432,
                             (size_t)256 * 2048 + 2 * (size_t)256 * 18432};
    const int tbo[4] = {0, 2048, 20480, 38912};
    int K = br ? 18432 : 2048;
    gemm_gather(Aall + aoffs[br], dtab + (size_t)tbo[br] * 8, xT,
                ypre + (size_t)br * 524288, K, zz * 1024, zz * 1024 + 1024,
                blockIdx.x * 128, blockIdx.y * 128);
}

// fuse GEMM: dense B [2048][1280] bf16, M=256, K=1280, kchunk=160, grid (16,2,8)
__global__ __launch_bounds__(256) void k_fgemm(const short* __restrict__ A,
                                               const short* __restrict__ Bp,
                                               float* __restrict__ C) {
    __shared__ __align__(16) short At[128][40];
    __shared__ __align__(16) short Bt[128][40];
    int t = threadIdx.x;
    int nbase = blockIdx.x * 128, mbase = blockIdx.y * 128;
    int kbeg = blockIdx.z * 160, kend = kbeg + 160;
    const int K = 1280;
    f32x4 acc[4][4] = {};
    int lane = t & 63, wv = t >> 6;
    int mq = (wv >> 1) * 64, nq = (wv & 1) * 64;
    int lm = lane & 15, quad = lane >> 4;
    for (int k0 = kbeg; k0 < kend; k0 += 32) {
        int row = t >> 2, seg = t & 3;
        *(uint4*)&At[row][seg * 8] = *(const uint4*)(A + (size_t)(mbase + row) * K + k0 + seg * 8);
        *(uint4*)&At[row + 64][seg * 8] = *(const uint4*)(A + (size_t)(mbase + row + 64) * K + k0 + seg * 8);
        *(uint4*)&Bt[row][seg * 8] = *(const uint4*)(Bp + (size_t)(nbase + row) * K + k0 + seg * 8);
        *(uint4*)&Bt[row + 64][seg * 8] = *(const uint4*)(Bp + (size_t)(nbase + row + 64) * K + k0 + seg * 8);
        __syncthreads();
        bf16x8 af[4], bfr[4];
        #pragma unroll
        for (int f = 0; f < 4; f++) {
            af[f]  = *(const bf16x8*)&At[mq + f * 16 + lm][quad * 8];
            bfr[f] = *(const bf16x8*)&Bt[nq + f * 16 + lm][quad * 8];
        }
        #pragma unroll
        for (int fm = 0; fm < 4; fm++)
            #pragma unroll
            for (int fn = 0; fn < 4; fn++)
                acc[fm][fn] = __builtin_amdgcn_mfma_f32_16x16x32_bf16(af[fm], bfr[fn], acc[fm][fn], 0, 0, 0);
        __syncthreads();
    }
    #pragma unroll
    for (int fm = 0; fm < 4; fm++) {
        int row0 = mbase + mq + fm * 16 + quad * 4;
        #pragma unroll
        for (int fn = 0; fn < 4; fn++) {
            int col = nbase + nq + fn * 16 + lm;
            #pragma unroll
            for (int r = 0; r < 4; r++)
                atomicAdd(&C[(size_t)(row0 + r) * 2048 + col], acc[fm][fn][r]);
        }
    }
}

// ---------------- BN stats ----------------
__global__ void k_bnstats(const float* Y0, const float* Y1, const float* Y2, const float* Y3,
                          const float* g0, const float* g1, const float* g2, const float* g3,
                          const float* b0, const float* b1, const float* b2, const float* b3,
                          float* S) {
    int br = blockIdx.y;
    const float* Y = br == 0 ? Y0 : br == 1 ? Y1 : br == 2 ? Y2 : Y3;
    const float* g = br == 0 ? g0 : br == 1 ? g1 : br == 2 ? g2 : g3;
    const float* b = br == 0 ? b0 : br == 1 ? b1 : br == 2 ? b2 : b3;
    float* so = S + (size_t)br * 512;
    int o = blockIdx.x, t = threadIdx.x;
    const float* row = Y + (size_t)o * 2048;
    float s = 0.f, ss = 0.f;
    for (int i = t; i < 2048; i += 256) { float v = row[i]; s += v; ss += v * v; }
    #pragma unroll
    for (int off = 32; off; off >>= 1) { s += __shfl_down(s, off); ss += __shfl_down(ss, off); }
    __shared__ float ls[4], lss[4];
    int wv = t >> 6;
    if ((t & 63) == 0) { ls[wv] = s; lss[wv] = ss; }
    __syncthreads();
    if (t == 0) {
        s = ls[0] + ls[1] + ls[2] + ls[3];
        ss = lss[0] + lss[1] + lss[2] + lss[3];
        float mu = s * (1.f / 2048.f);
        float var = ss * (1.f / 2048.f) - mu * mu;
        float sc = g[o] * rsqrtf(var + EPSV);
        so[o] = sc;
        so[256 + o] = b[o] - mu * sc;
    }
}

// ---------------- global average pool ----------------
__global__ void k_gap(const float* X, float* gap) {
    int bc = blockIdx.x;
    const float* row = X + (size_t)bc * 1024;
    int t = threadIdx.x;
    float s = row[t] + row[t + 256] + row[t + 512] + row[t + 768];
    #pragma unroll
    for (int off = 32; off; off >>= 1) s += __shfl_down(s, off);
    __shared__ float ls[4];
    if ((t & 63) == 0) ls[t >> 6] = s;
    __syncthreads();
    if (t == 0) gap[bc] = (ls[0] + ls[1] + ls[2] + ls[3]) * (1.f / 1024.f);
}

// ---------------- pool 1x1 conv + BN over batch + relu ----------------
__global__ void k_pool(const float* gap, const float* wpool, const float* gp, const float* bp,
                       float* pfin) {
    int o = blockIdx.x, t = threadIdx.x;
    float s0 = 0.f, s1 = 0.f;
    const float* wr = wpool + (size_t)o * 2048;
    for (int c = t; c < 2048; c += 256) {
        float wv = wr[c];
        s0 += wv * gap[c];
        s1 += wv * gap[2048 + c];
    }
    #pragma unroll
    for (int off = 32; off; off >>= 1) { s0 += __shfl_down(s0, off); s1 += __shfl_down(s1, off); }
    __shared__ float l0[4], l1[4];
    int wv_ = t >> 6;
    if ((t & 63) == 0) { l0[wv_] = s0; l1[wv_] = s1; }
    __syncthreads();
    if (t == 0) {
        float p0 = l0[0] + l0[1] + l0[2] + l0[3];
        float p1 = l1[0] + l1[1] + l1[2] + l1[3];
        float mu = 0.5f * (p0 + p1);
        float d0 = p0 - mu, d1 = p1 - mu;
        float var = 0.5f * (d0 * d0 + d1 * d1);
        float r = rsqrtf(var + EPSV);
        pfin[o]       = fmaxf(d0 * r * gp[o] + bp[o], 0.f);
        pfin[256 + o] = fmaxf(d1 * r * gp[o] + bp[o], 0.f);
    }
}

// ---------------- build fuse-GEMM B matrix: [2048 positions][1280] bf16 ----------------
__global__ void k_xcat(const float* ypre, const float* S, const float* pfin, short* xcat) {
    int pidx = blockIdx.x;
    int b = pidx >> 10;
    int t = threadIdx.x;
    for (int c = t; c < 1280; c += 256) {
        float v;
        if (c < 1024) {
            int br = c >> 8, cc = c & 255;
            float sc = S[(size_t)br * 512 + cc], sh = S[(size_t)br * 512 + 256 + cc];
            v = fmaxf(ypre[((size_t)br * 256 + cc) * 2048 + pidx] * sc + sh, 0.f);
        } else {
            v = pfin[b * 256 + (c - 1024)];
        }
        xcat[(size_t)pidx * 1280 + c] = f2bf(v);
    }
}

// ---------------- final BN + relu + layout to [B][O][HW] ----------------
__global__ void k_final(const float* outpre, const float* S, float* dout) {
    int i = blockIdx.x * 256 + threadIdx.x;    // 524288
    int hw = i & 1023, o = (i >> 10) & 255, b = i >> 18;
    float v = outpre[(size_t)o * 2048 + b * 1024 + hw] * S[o] + S[256 + o];
    dout[i] = fmaxf(v, 0.f);
}

extern "C" void kernel_launch(void* const* d_in, const int* in_sizes, int n_in,
                              void* d_out, int out_size, void* d_ws, size_t ws_size,
                              hipStream_t stream) {
    const float* x     = (const float*)d_in[0];
    const float* woff1 = (const float*)d_in[1];
    const float* wm1   = (const float*)d_in[2];
    const float* w1    = (const float*)d_in[3];
    const float* g1    = (const float*)d_in[4];
    const float* b1    = (const float*)d_in[5];
    const float* woff2 = (const float*)d_in[6];
    const float* wm2   = (const float*)d_in[7];
    const float* w2    = (const float*)d_in[8];
    const float* g2    = (const float*)d_in[9];
    const float* b2    = (const float*)d_in[10];
    const float* woff3 = (const float*)d_in[11];
    const float* wm3   = (const float*)d_in[12];
    const float* w3    = (const float*)d_in[13];
    const float* g3    = (const float*)d_in[14];
    const float* b3    = (const float*)d_in[15];
    const float* woff4 = (const float*)d_in[16];
    const float* wm4   = (const float*)d_in[17];
    const float* w4    = (const float*)d_in[18];
    const float* g4    = (const float*)d_in[19];
    const float* b4    = (const float*)d_in[20];
    const float* wpool = (const float*)d_in[21];
    const float* gp    = (const float*)d_in[22];
    const float* bp    = (const float*)d_in[23];
    const float* wfuse = (const float*)d_in[24];
    const float* gf    = (const float*)d_in[25];
    const float* bf    = (const float*)d_in[26];

    char* ws = (char*)d_ws;
    size_t off = 0;
    auto alloc = [&](size_t bytes) {
        off = (off + 255) & ~(size_t)255;
        size_t o = off; off += bytes; return o;
    };
    // zero-init region contiguous: offmod | ypre | outpre
    size_t off_offmod = alloc(128 * 2048 * 4);
    size_t off_ypre   = alloc((size_t)4 * 256 * 2048 * 4);
    size_t off_outpre = alloc(256 * 2048 * 4);
    // A1..A4 contiguous (Aall)
    size_t off_A1     = alloc((size_t)256 * 2048 * 2);
    size_t off_A2     = alloc((size_t)256 * 18432 * 2);
    size_t off_A3     = alloc((size_t)256 * 18432 * 2);
    size_t off_A4     = alloc((size_t)256 * 18432 * 2);
    size_t off_Aoff   = alloc((size_t)128 * 18432 * 2);
    size_t off_Afuse  = alloc((size_t)256 * 1280 * 2);
    size_t off_xcat   = alloc((size_t)2048 * 1280 * 2);
    size_t off_xT     = alloc((size_t)2 * 1024 * 2048 * 2);
    size_t off_dtab0  = alloc((size_t)9 * 2048 * 32);
    size_t off_dtab   = alloc((size_t)57344 * 32);
    size_t off_scsh   = alloc((size_t)4 * 512 * 4);
    size_t off_scshf  = alloc((size_t)512 * 4);
    size_t off_gap    = alloc((size_t)4096 * 4);
    size_t off_pfin   = alloc((size_t)512 * 4);
    (void)ws_size; (void)in_sizes; (void)n_in; (void)out_size;

    float* offmod = (float*)(ws + off_offmod);
    float* ypre   = (float*)(ws + off_ypre);
    float* outpre = (float*)(ws + off_outpre);
    short* Aall   = (short*)(ws + off_A1);
    short* A1     = (short*)(ws + off_A1);
    short* A2     = (short*)(ws + off_A2);
    short* A3     = (short*)(ws + off_A3);
    short* A4     = (short*)(ws + off_A4);
    short* Aoff   = (short*)(ws + off_Aoff);
    short* Afuse  = (short*)(ws + off_Afuse);
    short* xcat   = (short*)(ws + off_xcat);
    short* xT     = (short*)(ws + off_xT);
    int*   dtab0  = (int*)(ws + off_dtab0);
    int*   dtab   = (int*)(ws + off_dtab);
    float* scsh   = (float*)(ws + off_scsh);
    float* scshf  = (float*)(ws + off_scshf);
    float* gapb   = (float*)(ws + off_gap);
    float* pfin   = (float*)(ws + off_pfin);

    // 1. zero accumulators (offmod + ypre + outpre contiguous)
    k_zero<<<2048, 256, 0, stream>>>((float4*)(ws + off_offmod), 720896);
    // 2. transpose x -> NHWC bf16
    k_xpose<<<dim3(16, 32, 2), 256, 0, stream>>>(x, xT);
    // 3. weight conversions
    k_convw<<<dim3(18432, 4), 256, 0, stream>>>(w1, w2, w3, w4, A1, A2, A3, A4);
    k_convoff<<<9216, 256, 0, stream>>>(woff1, wm1, woff2, wm2, woff3, wm3, woff4, wm4, Aoff);
    k_afuse<<<1280, 256, 0, stream>>>(wfuse, Afuse);
    k_shtab<<<72, 256, 0, stream>>>(dtab0);
    // 4. offset/mod conv GEMM
    k_ogemm<<<dim3(16, 1, 36), 256, 0, stream>>>(Aoff, dtab0, xT, offmod);
    // 5. sampling tables
    k_sample<<<224, 256, 0, stream>>>(offmod, dtab);
    // 6. merged 4-branch deform GEMM
    k_dgemm<<<dim3(16, 2, 56), 256, 0, stream>>>(Aall, dtab, xT, ypre);
    // 7. branch BN stats
    k_bnstats<<<dim3(256, 4), 256, 0, stream>>>(ypre, ypre + 524288, ypre + 2 * 524288, ypre + 3 * 524288,
                                                g1, g2, g3, g4, b1, b2, b3, b4, scsh);
    // 8. pool branch
    k_gap<<<4096, 256, 0, stream>>>(x, gapb);
    k_pool<<<256, 256, 0, stream>>>(gapb, wpool, gp, bp, pfin);
    // 9. concat (BN+relu applied) as bf16 [2048][1280]
    k_xcat<<<2048, 256, 0, stream>>>(ypre, scsh, pfin, xcat);
    // 10. fuse GEMM
    k_fgemm<<<dim3(16, 2, 8), 256, 0, stream>>>(Afuse, xcat, outpre);
    // 11. final BN stats + apply
    k_bnstats<<<dim3(256, 1), 256, 0, stream>>>(outpre, outpre, outpre, outpre,
                                                gf, gf, gf, gf, bf, bf, bf, bf, scshf);
    k_final<<<2048, 256, 0, stream>>>(outpre, scshf, (float*)d_out);
}

// Round 3
// 427.971 us; speedup vs baseline: 3.1085x; 1.1271x over previous
//
#include <hip/hip_runtime.h>
#include <hip/hip_fp16.h>
#include <cstdint>
#include <cstddef>

#define EPSV 1e-5f

typedef _Float16 f16x8 __attribute__((ext_vector_type(8)));
typedef float f32x4 __attribute__((ext_vector_type(4)));

__device__ __forceinline__ short f2h(float f) {
    _Float16 h = (_Float16)f;
    union { _Float16 h; short s; } u; u.h = h; return u.s;
}
__device__ __forceinline__ __half2 u2h2(unsigned u) {
    union { unsigned u; __half2 h; } x; x.u = u; return x.h;
}
__device__ __forceinline__ unsigned packh2(float w) {
    _Float16 h = (_Float16)w;
    union { _Float16 h; unsigned short s; } u; u.h = h;
    return (unsigned)u.s * 0x10001u;
}

// ---------------- zero init ----------------
__global__ void k_zero(float4* p, int n4) {
    int i = blockIdx.x * blockDim.x + threadIdx.x;
    int stride = gridDim.x * blockDim.x;
    for (; i < n4; i += stride) p[i] = float4{0.f, 0.f, 0.f, 0.f};
}

// ---------------- transpose x: [B][C][HW] f32 -> xT [B][HW][C] f16 ----------------
__global__ void k_xpose(const float* __restrict__ x, short* __restrict__ xT) {
    int hw0 = blockIdx.x * 64, c0 = blockIdx.y * 64, b = blockIdx.z;
    __shared__ short tile[64][72];
    int t = threadIdx.x;
    const float* xb = x + (size_t)b * 2048 * 1024;
    int hwi = t & 63, cr = t >> 6;
    #pragma unroll
    for (int r = 0; r < 16; r++) {
        int cl = cr + r * 4;
        tile[hwi][cl] = f2h(xb[(size_t)(c0 + cl) * 1024 + hw0 + hwi]);
    }
    __syncthreads();
    short* xTb = xT + (size_t)b * 1024 * 2048;
    int ci = t & 63, hr = t >> 6;
    #pragma unroll
    for (int r = 0; r < 16; r++) {
        int hwr = hr + r * 4;
        xTb[(size_t)(hw0 + hwr) * 2048 + c0 + ci] = tile[hwr][ci];
    }
}

// ---------------- w1 (k=1): straight convert [256][2048] ----------------
__global__ void k_convw1(const float* __restrict__ w1, short* __restrict__ A1) {
    int i = blockIdx.x * 256 + threadIdx.x;
    if (i < 256 * 2048) A1[i] = f2h(w1[i]);
}

// ---------------- 3x3 branch weights: [o][c][9] f32 -> [o][j*2048+c] f16, LDS transpose ----------------
__global__ void k_convw9(const float* w2, const float* w3, const float* w4,
                         short* A2, short* A3, short* A4) {
    int o = blockIdx.x, cch = blockIdx.y, br = blockIdx.z;
    const float* src = br == 0 ? w2 : br == 1 ? w3 : w4;
    short* dst = br == 0 ? A2 : br == 1 ? A3 : A4;
    __shared__ short lds[4608];
    int t = threadIdx.x;
    const float* basep = src + ((size_t)o * 2048 + cch * 512) * 9;
    #pragma unroll
    for (int s = 0; s < 18; s++) {
        int idx = s * 256 + t;
        int c = idx / 9, jj = idx - c * 9;
        lds[jj * 512 + c] = f2h(basep[idx]);
    }
    __syncthreads();
    short* dbase = dst + (size_t)o * 18432 + cch * 512;
    #pragma unroll
    for (int s = 0; s < 18; s++) {
        int idx = s * 256 + t;
        int jj = idx >> 9, c = idx & 511;
        dbase[(size_t)jj * 2048 + c] = lds[idx];
    }
}

// ---------------- offset/mod weights -> Aoff[128][j*2048+c] f16, LDS transpose ----------------
__global__ void k_convoff(const float* woff1, const float* wm1, const float* woff2, const float* wm2,
                          const float* woff3, const float* wm3, const float* woff4, const float* wm4,
                          short* Aoff) {
    int ch = blockIdx.x, cch = blockIdx.y;
    int t = threadIdx.x;
    short* dbase = Aoff + (size_t)ch * 18432 + cch * 512;
    if (ch >= 84) {
        #pragma unroll
        for (int s = 0; s < 18; s++) {
            int idx = s * 256 + t;
            int jj = idx >> 9, c = idx & 511;
            dbase[(size_t)jj * 2048 + c] = 0;
        }
        return;
    }
    const float* src; int oc;
    if (ch < 2)       { src = woff1; oc = ch; }
    else if (ch == 2) { src = wm1;   oc = 0; }
    else if (ch < 21) { src = woff2; oc = ch - 3; }
    else if (ch < 30) { src = wm2;   oc = ch - 21; }
    else if (ch < 48) { src = woff3; oc = ch - 30; }
    else if (ch < 57) { src = wm3;   oc = ch - 48; }
    else if (ch < 75) { src = woff4; oc = ch - 57; }
    else              { src = wm4;   oc = ch - 75; }
    __shared__ short lds[4608];
    const float* basep = src + ((size_t)oc * 2048 + cch * 512) * 9;
    #pragma unroll
    for (int s = 0; s < 18; s++) {
        int idx = s * 256 + t;
        int c = idx / 9, jj = idx - c * 9;
        lds[jj * 512 + c] = f2h(basep[idx]);
    }
    __syncthreads();
    #pragma unroll
    for (int s = 0; s < 18; s++) {
        int idx = s * 256 + t;
        int jj = idx >> 9, c = idx & 511;
        dbase[(size_t)jj * 2048 + c] = lds[idx];
    }
}

__global__ void k_afuse(const float* wfuse, short* Af) {
    int i = blockIdx.x * 256 + threadIdx.x;
    if (i < 256 * 1280) Af[i] = f2h(wfuse[i]);
}

// ---------------- synthetic 1-tap table for the 3x3 pad-1 offset conv ----------------
__global__ void k_shtab(int* dtab0) {
    int i = blockIdx.x * 256 + threadIdx.x;   // 9*2048
    if (i >= 9 * 2048) return;
    int j = i >> 11, p = i & 2047;
    int hw = p & 1023, h = hw >> 5, w = hw & 31;
    int y = h + j / 3 - 1, xx = w + j % 3 - 1;
    bool v = (y >= 0 && y < 32 && xx >= 0 && xx < 32);
    int4 ii = {v ? y * 32 + xx : 0, 0, 0, 0};
    uint4 ww = {v ? packh2(1.f) : 0u, 0u, 0u, 0u};
    ((int4*)dtab0)[(size_t)i * 2] = ii;
    ((uint4*)dtab0)[(size_t)i * 2 + 1] = ww;
}

// ---------------- deform sampling tables (ii + packed-f16 tap weights) ----------------
__global__ void k_sample(const float* OM, int* dtabi) {
    int i = blockIdx.x * 256 + threadIdx.x;
    if (i >= 57344) return;
    int br, j, p;
    if (i < 2048) { br = 0; j = 0; p = i; }
    else { int r = i - 2048; br = 1 + r / 18432; r %= 18432; j = r >> 11; p = r & 2047; }
    const int dil_[4] = {1, 6, 12, 18};
    const int pad_[4] = {0, 6, 12, 18};
    const int cho_[4] = {0, 3, 30, 57};
    const int chm_[4] = {2, 21, 48, 75};
    const int tbo_[4] = {0, 2048, 20480, 38912};
    int J = br ? 9 : 1;
    int dil = dil_[br], pad = pad_[br];
    int hw = p & 1023, h = hw >> 5, w = hw & 31;
    float offy = OM[(size_t)(cho_[br] + j) * 2048 + p];
    float offx = OM[(size_t)(cho_[br] + J + j) * 2048 + p];
    float mz   = OM[(size_t)(chm_[br] + j) * 2048 + p];
    float m = 1.f / (1.f + expf(-mz));
    int ky = j / 3, kx = j - ky * 3;
    float fh = (float)(h + ky * dil) + offy;
    float fw = (float)(w + kx * dil) + offx;
    int limi = 31 + 2 * pad;
    float lim = (float)limi;
    fh = fminf(fmaxf(fh, 0.f), lim);
    fw = fminf(fmaxf(fw, 0.f), lim);
    float y0f = floorf(fh), x0f = floorf(fw);
    float wy = fh - y0f, wx = fw - x0f;
    int y0 = (int)y0f, x0 = (int)x0f;
    int y1 = min(y0 + 1, limi), x1 = min(x0 + 1, limi);
    int4 ii; uint4 ww;
    {
        int yo = y0 - pad, xo = x0 - pad;
        bool v = ((unsigned)yo < 32u) && ((unsigned)xo < 32u);
        ii.x = v ? yo * 32 + xo : 0; ww.x = v ? packh2((1.f - wy) * (1.f - wx) * m) : 0u;
    }
    {
        int yo = y0 - pad, xo = x1 - pad;
        bool v = ((unsigned)yo < 32u) && ((unsigned)xo < 32u);
        ii.y = v ? yo * 32 + xo : 0; ww.y = v ? packh2((1.f - wy) * wx * m) : 0u;
    }
    {
        int yo = y1 - pad, xo = x0 - pad;
        bool v = ((unsigned)yo < 32u) && ((unsigned)xo < 32u);
        ii.z = v ? yo * 32 + xo : 0; ww.z = v ? packh2(wy * (1.f - wx) * m) : 0u;
    }
    {
        int yo = y1 - pad, xo = x1 - pad;
        bool v = ((unsigned)yo < 32u) && ((unsigned)xo < 32u);
        ii.w = v ? yo * 32 + xo : 0; ww.w = v ? packh2(wy * wx * m) : 0u;
    }
    int ent = tbo_[br] + j * 2048 + p;
    ((int4*)dtabi)[(size_t)ent * 2] = ii;
    ((uint4*)dtabi)[(size_t)ent * 2 + 1] = ww;
}

// ---------------- gather GEMM body: (WM*64)x128 tile, BK=32, 16x16x32 f16 ----------------
// B[k=(j,c)][p] = sum_tap ww[tap] * xT[b][ii[tap]][c], tap-combine via v_pk_fma_f16.
template <int WM>
__device__ __forceinline__ void gemm_gather_f16(
    const short* __restrict__ A, const int* __restrict__ tab,
    const short* __restrict__ xT, float* __restrict__ C,
    int K, int kbeg, int kend, int nbase)
{
    constexpr int TPB = WM * 128;       // threads
    constexpr int TPP = TPB / 128;      // threads per position
    constexpr int CPT = 32 / TPP;       // channels per thread (8 or 16)
    constexpr int NG = CPT / 8;         // uint4 groups per tap
    __shared__ __align__(16) short At[WM * 64][40];
    __shared__ __align__(16) short Bt[128][40];
    int t = threadIdx.x;
    f32x4 acc[4][4] = {};

    int p = t / TPP;
    int q = (t % TPP) * CPT;
    int pg = nbase + p;
    int bb = nbase >> 10;
    int jj = kbeg >> 11;
    const int4* te = (const int4*)tab + ((size_t)jj * 2048 + pg) * 2;
    int4 ii = te[0];
    uint4 wp = *(const uint4*)(te + 1);
    __half2 wt0 = u2h2(wp.x), wt1 = u2h2(wp.y), wt2 = u2h2(wp.z), wt3 = u2h2(wp.w);
    const short* xbase = xT + (size_t)bb * 1024 * 2048 + q;
    const short* rp0 = xbase + (size_t)ii.x * 2048;
    const short* rp1 = xbase + (size_t)ii.y * 2048;
    const short* rp2 = xbase + (size_t)ii.z * 2048;
    const short* rp3 = xbase + (size_t)ii.w * 2048;

    int arow = t >> 1;
    int aseg = (t & 1) * 16;
    const short* Ar = A + (size_t)arow * K + aseg;

    int lane = t & 63, wv = t >> 6;
    int mq = (wv >> 1) * 64, nq = (wv & 1) * 64;
    int lm = lane & 15, quad = lane >> 4;

    for (int k0 = kbeg; k0 < kend; k0 += 32) {
        // stage A tile
        *(uint4*)&At[arow][aseg]     = *(const uint4*)(Ar + k0);
        *(uint4*)&At[arow][aseg + 8] = *(const uint4*)(Ar + k0 + 8);
        // stage B tile: 4-tap packed-f16 bilinear combine
        {
            int ck = k0 & 2047;
            #pragma unroll
            for (int g = 0; g < NG; g++) {
                __half2 a0 = u2h2(0u), a1 = u2h2(0u), a2 = u2h2(0u), a3 = u2h2(0u);
                int cko = ck + g * 8;
                uint4 d0 = *(const uint4*)(rp0 + cko);
                a0 = __hfma2(u2h2(d0.x), wt0, a0); a1 = __hfma2(u2h2(d0.y), wt0, a1);
                a2 = __hfma2(u2h2(d0.z), wt0, a2); a3 = __hfma2(u2h2(d0.w), wt0, a3);
                uint4 d1 = *(const uint4*)(rp1 + cko);
                a0 = __hfma2(u2h2(d1.x), wt1, a0); a1 = __hfma2(u2h2(d1.y), wt1, a1);
                a2 = __hfma2(u2h2(d1.z), wt1, a2); a3 = __hfma2(u2h2(d1.w), wt1, a3);
                uint4 d2 = *(const uint4*)(rp2 + cko);
                a0 = __hfma2(u2h2(d2.x), wt2, a0); a1 = __hfma2(u2h2(d2.y), wt2, a1);
                a2 = __hfma2(u2h2(d2.z), wt2, a2); a3 = __hfma2(u2h2(d2.w), wt2, a3);
                uint4 d3 = *(const uint4*)(rp3 + cko);
                a0 = __hfma2(u2h2(d3.x), wt3, a0); a1 = __hfma2(u2h2(d3.y), wt3, a1);
                a2 = __hfma2(u2h2(d3.z), wt3, a2); a3 = __hfma2(u2h2(d3.w), wt3, a3);
                union { __half2 h[4]; uint4 u; } pk;
                pk.h[0] = a0; pk.h[1] = a1; pk.h[2] = a2; pk.h[3] = a3;
                *(uint4*)&Bt[p][q + g * 8] = pk.u;
            }
        }
        __syncthreads();
        f16x8 af[4], bfv[4];
        #pragma unroll
        for (int f = 0; f < 4; f++) {
            af[f]  = *(const f16x8*)&At[mq + f * 16 + lm][quad * 8];
            bfv[f] = *(const f16x8*)&Bt[nq + f * 16 + lm][quad * 8];
        }
        #pragma unroll
        for (int fm = 0; fm < 4; fm++)
            #pragma unroll
            for (int fn = 0; fn < 4; fn++)
                acc[fm][fn] = __builtin_amdgcn_mfma_f32_16x16x32_f16(af[fm], bfv[fn], acc[fm][fn], 0, 0, 0);
        __syncthreads();
    }
    #pragma unroll
    for (int fm = 0; fm < 4; fm++) {
        int row0 = mq + fm * 16 + quad * 4;
        #pragma unroll
        for (int fn = 0; fn < 4; fn++) {
            int col = nbase + nq + fn * 16 + lm;
            #pragma unroll
            for (int r = 0; r < 4; r++)
                atomicAdd(&C[(size_t)(row0 + r) * 2048 + col], acc[fm][fn][r]);
        }
    }
}

// offset/mod conv GEMM: M=128, K=18432, kchunk=1024, grid (16,1,18), block 256
__global__ __launch_bounds__(256) void k_ogemm(const short* __restrict__ Aoff,
                                               const int* __restrict__ dtab0,
                                               const short* __restrict__ xT,
                                               float* __restrict__ offmod) {
    int kbeg = blockIdx.z * 1024;
    gemm_gather_f16<2>(Aoff, dtab0, xT, offmod, 18432, kbeg, kbeg + 1024, blockIdx.x * 128);
}

// merged 4-branch deform GEMM: M=256, kchunk=1024, grid (16,1,56), block 512
__global__ __launch_bounds__(512) void k_dgemm(const short* __restrict__ Aall,
                                               const int* __restrict__ dtab,
                                               const short* __restrict__ xT,
                                               float* __restrict__ ypre) {
    int z = blockIdx.z;
    int br, kbeg;
    if (z < 2) { br = 0; kbeg = z * 1024; }
    else { int zz = z - 2; br = 1 + zz / 18; kbeg = (zz % 18) * 1024; }
    const size_t aoffs[4] = {0, 524288, 524288 + 4718592, 524288 + 2 * (size_t)4718592};
    const int tbo[4] = {0, 2048, 20480, 38912};
    int K = br ? 18432 : 2048;
    gemm_gather_f16<4>(Aall + aoffs[br], dtab + (size_t)tbo[br] * 8, xT,
                       ypre + (size_t)br * 524288, K, kbeg, kbeg + 1024, blockIdx.x * 128);
}

// fuse GEMM: dense B [2048][1280] f16, M=256, K=1280, kchunk=160, grid (16,2,8)
__global__ __launch_bounds__(256) void k_fgemm(const short* __restrict__ A,
                                               const short* __restrict__ Bp,
                                               float* __restrict__ C) {
    __shared__ __align__(16) short At[128][40];
    __shared__ __align__(16) short Bt[128][40];
    int t = threadIdx.x;
    int nbase = blockIdx.x * 128, mbase = blockIdx.y * 128;
    int kbeg = blockIdx.z * 160, kend = kbeg + 160;
    const int K = 1280;
    f32x4 acc[4][4] = {};
    int lane = t & 63, wv = t >> 6;
    int mq = (wv >> 1) * 64, nq = (wv & 1) * 64;
    int lm = lane & 15, quad = lane >> 4;
    for (int k0 = kbeg; k0 < kend; k0 += 32) {
        int row = t >> 2, seg = t & 3;
        *(uint4*)&At[row][seg * 8] = *(const uint4*)(A + (size_t)(mbase + row) * K + k0 + seg * 8);
        *(uint4*)&At[row + 64][seg * 8] = *(const uint4*)(A + (size_t)(mbase + row + 64) * K + k0 + seg * 8);
        *(uint4*)&Bt[row][seg * 8] = *(const uint4*)(Bp + (size_t)(nbase + row) * K + k0 + seg * 8);
        *(uint4*)&Bt[row + 64][seg * 8] = *(const uint4*)(Bp + (size_t)(nbase + row + 64) * K + k0 + seg * 8);
        __syncthreads();
        f16x8 af[4], bfv[4];
        #pragma unroll
        for (int f = 0; f < 4; f++) {
            af[f]  = *(const f16x8*)&At[mq + f * 16 + lm][quad * 8];
            bfv[f] = *(const f16x8*)&Bt[nq + f * 16 + lm][quad * 8];
        }
        #pragma unroll
        for (int fm = 0; fm < 4; fm++)
            #pragma unroll
            for (int fn = 0; fn < 4; fn++)
                acc[fm][fn] = __builtin_amdgcn_mfma_f32_16x16x32_f16(af[fm], bfv[fn], acc[fm][fn], 0, 0, 0);
        __syncthreads();
    }
    #pragma unroll
    for (int fm = 0; fm < 4; fm++) {
        int row0 = mbase + mq + fm * 16 + quad * 4;
        #pragma unroll
        for (int fn = 0; fn < 4; fn++) {
            int col = nbase + nq + fn * 16 + lm;
            #pragma unroll
            for (int r = 0; r < 4; r++)
                atomicAdd(&C[(size_t)(row0 + r) * 2048 + col], acc[fm][fn][r]);
        }
    }
}

// ---------------- BN stats ----------------
__global__ void k_bnstats(const float* Y0, const float* Y1, const float* Y2, const float* Y3,
                          const float* g0, const float* g1, const float* g2, const float* g3,
                          const float* b0, const float* b1, const float* b2, const float* b3,
                          float* S) {
    int br = blockIdx.y;
    const float* Y = br == 0 ? Y0 : br == 1 ? Y1 : br == 2 ? Y2 : Y3;
    const float* g = br == 0 ? g0 : br == 1 ? g1 : br == 2 ? g2 : g3;
    const float* b = br == 0 ? b0 : br == 1 ? b1 : br == 2 ? b2 : b3;
    float* so = S + (size_t)br * 512;
    int o = blockIdx.x, t = threadIdx.x;
    const float* row = Y + (size_t)o * 2048;
    float s = 0.f, ss = 0.f;
    for (int i = t; i < 2048; i += 256) { float v = row[i]; s += v; ss += v * v; }
    #pragma unroll
    for (int off = 32; off; off >>= 1) { s += __shfl_down(s, off); ss += __shfl_down(ss, off); }
    __shared__ float ls[4], lss[4];
    int wv = t >> 6;
    if ((t & 63) == 0) { ls[wv] = s; lss[wv] = ss; }
    __syncthreads();
    if (t == 0) {
        s = ls[0] + ls[1] + ls[2] + ls[3];
        ss = lss[0] + lss[1] + lss[2] + lss[3];
        float mu = s * (1.f / 2048.f);
        float var = ss * (1.f / 2048.f) - mu * mu;
        float sc = g[o] * rsqrtf(var + EPSV);
        so[o] = sc;
        so[256 + o] = b[o] - mu * sc;
    }
}

// ---------------- global average pool ----------------
__global__ void k_gap(const float* X, float* gap) {
    int bc = blockIdx.x;
    const float* row = X + (size_t)bc * 1024;
    int t = threadIdx.x;
    float s = row[t] + row[t + 256] + row[t + 512] + row[t + 768];
    #pragma unroll
    for (int off = 32; off; off >>= 1) s += __shfl_down(s, off);
    __shared__ float ls[4];
    if ((t & 63) == 0) ls[t >> 6] = s;
    __syncthreads();
    if (t == 0) gap[bc] = (ls[0] + ls[1] + ls[2] + ls[3]) * (1.f / 1024.f);
}

// ---------------- pool 1x1 conv + BN over batch + relu ----------------
__global__ void k_pool(const float* gap, const float* wpool, const float* gp, const float* bp,
                       float* pfin) {
    int o = blockIdx.x, t = threadIdx.x;
    float s0 = 0.f, s1 = 0.f;
    const float* wr = wpool + (size_t)o * 2048;
    for (int c = t; c < 2048; c += 256) {
        float wv = wr[c];
        s0 += wv * gap[c];
        s1 += wv * gap[2048 + c];
    }
    #pragma unroll
    for (int off = 32; off; off >>= 1) { s0 += __shfl_down(s0, off); s1 += __shfl_down(s1, off); }
    __shared__ float l0[4], l1[4];
    int wv_ = t >> 6;
    if ((t & 63) == 0) { l0[wv_] = s0; l1[wv_] = s1; }
    __syncthreads();
    if (t == 0) {
        float p0 = l0[0] + l0[1] + l0[2] + l0[3];
        float p1 = l1[0] + l1[1] + l1[2] + l1[3];
        float mu = 0.5f * (p0 + p1);
        float d0 = p0 - mu, d1 = p1 - mu;
        float var = 0.5f * (d0 * d0 + d1 * d1);
        float r = rsqrtf(var + EPSV);
        pfin[o]       = fmaxf(d0 * r * gp[o] + bp[o], 0.f);
        pfin[256 + o] = fmaxf(d1 * r * gp[o] + bp[o], 0.f);
    }
}

// ---------------- xcat transpose: ypre[1024ch][2048p] (BN+relu) + pfin -> xcat[p][1280] f16 ----------------
__global__ void k_xcat(const float* __restrict__ ypre, const float* __restrict__ S,
                       const float* __restrict__ pfin, short* __restrict__ xcat) {
    int p0 = blockIdx.x * 64, ct = blockIdx.y;
    int t = threadIdx.x;
    if (ct >= 16) {
        int c0 = 1024 + (ct - 16) * 64;
        int ci = t & 63, pr = t >> 6;
        #pragma unroll
        for (int r = 0; r < 16; r++) {
            int pw = p0 + pr + r * 4;
            int b = pw >> 10;
            xcat[(size_t)pw * 1280 + c0 + ci] = f2h(pfin[b * 256 + (c0 - 1024) + ci]);
        }
        return;
    }
    __shared__ short tile[64][72];
    int c0 = ct * 64;
    int pi = t & 63, cr = t >> 6;
    #pragma unroll
    for (int r = 0; r < 16; r++) {
        int cl = cr + r * 4;
        int cg = c0 + cl;
        int br = cg >> 8, cc = cg & 255;
        float sc = S[br * 512 + cc], sh = S[br * 512 + 256 + cc];
        float v = fmaxf(ypre[(size_t)cg * 2048 + p0 + pi] * sc + sh, 0.f);
        tile[pi][cl] = f2h(v);
    }
    __syncthreads();
    int ci = t & 63, pr = t >> 6;
    #pragma unroll
    for (int r = 0; r < 16; r++) {
        int pw = pr + r * 4;
        xcat[(size_t)(p0 + pw) * 1280 + c0 + ci] = tile[pw][ci];
    }
}

// ---------------- final BN + relu + layout to [B][O][HW] ----------------
__global__ void k_final(const float* outpre, const float* S, float* dout) {
    int i = blockIdx.x * 256 + threadIdx.x;    // 524288
    int hw = i & 1023, o = (i >> 10) & 255, b = i >> 18;
    float v = outpre[(size_t)o * 2048 + b * 1024 + hw] * S[o] + S[256 + o];
    dout[i] = fmaxf(v, 0.f);
}

extern "C" void kernel_launch(void* const* d_in, const int* in_sizes, int n_in,
                              void* d_out, int out_size, void* d_ws, size_t ws_size,
                              hipStream_t stream) {
    const float* x     = (const float*)d_in[0];
    const float* woff1 = (const float*)d_in[1];
    const float* wm1   = (const float*)d_in[2];
    const float* w1    = (const float*)d_in[3];
    const float* g1    = (const float*)d_in[4];
    const float* b1    = (const float*)d_in[5];
    const float* woff2 = (const float*)d_in[6];
    const float* wm2   = (const float*)d_in[7];
    const float* w2    = (const float*)d_in[8];
    const float* g2    = (const float*)d_in[9];
    const float* b2    = (const float*)d_in[10];
    const float* woff3 = (const float*)d_in[11];
    const float* wm3   = (const float*)d_in[12];
    const float* w3    = (const float*)d_in[13];
    const float* g3    = (const float*)d_in[14];
    const float* b3    = (const float*)d_in[15];
    const float* woff4 = (const float*)d_in[16];
    const float* wm4   = (const float*)d_in[17];
    const float* w4    = (const float*)d_in[18];
    const float* g4    = (const float*)d_in[19];
    const float* b4    = (const float*)d_in[20];
    const float* wpool = (const float*)d_in[21];
    const float* gp    = (const float*)d_in[22];
    const float* bp    = (const float*)d_in[23];
    const float* wfuse = (const float*)d_in[24];
    const float* gf    = (const float*)d_in[25];
    const float* bf    = (const float*)d_in[26];

    char* ws = (char*)d_ws;
    size_t off = 0;
    auto alloc = [&](size_t bytes) {
        off = (off + 255) & ~(size_t)255;
        size_t o = off; off += bytes; return o;
    };
    // zero-init region contiguous: offmod | ypre | outpre
    size_t off_offmod = alloc(128 * 2048 * 4);
    size_t off_ypre   = alloc((size_t)4 * 256 * 2048 * 4);
    size_t off_outpre = alloc(256 * 2048 * 4);
    // A1..A4 contiguous (Aall)
    size_t off_A1     = alloc((size_t)256 * 2048 * 2);
    size_t off_A2     = alloc((size_t)256 * 18432 * 2);
    size_t off_A3     = alloc((size_t)256 * 18432 * 2);
    size_t off_A4     = alloc((size_t)256 * 18432 * 2);
    size_t off_Aoff   = alloc((size_t)128 * 18432 * 2);
    size_t off_Afuse  = alloc((size_t)256 * 1280 * 2);
    size_t off_xcat   = alloc((size_t)2048 * 1280 * 2);
    size_t off_xT     = alloc((size_t)2 * 1024 * 2048 * 2);
    size_t off_dtab0  = alloc((size_t)9 * 2048 * 32);
    size_t off_dtab   = alloc((size_t)57344 * 32);
    size_t off_scsh   = alloc((size_t)4 * 512 * 4);
    size_t off_scshf  = alloc((size_t)512 * 4);
    size_t off_gap    = alloc((size_t)4096 * 4);
    size_t off_pfin   = alloc((size_t)512 * 4);
    (void)ws_size; (void)in_sizes; (void)n_in; (void)out_size;

    float* offmod = (float*)(ws + off_offmod);
    float* ypre   = (float*)(ws + off_ypre);
    float* outpre = (float*)(ws + off_outpre);
    short* Aall   = (short*)(ws + off_A1);
    short* A1     = (short*)(ws + off_A1);
    short* A2     = (short*)(ws + off_A2);
    short* A3     = (short*)(ws + off_A3);
    short* A4     = (short*)(ws + off_A4);
    short* Aoff   = (short*)(ws + off_Aoff);
    short* Afuse  = (short*)(ws + off_Afuse);
    short* xcat   = (short*)(ws + off_xcat);
    short* xT     = (short*)(ws + off_xT);
    int*   dtab0  = (int*)(ws + off_dtab0);
    int*   dtab   = (int*)(ws + off_dtab);
    float* scsh   = (float*)(ws + off_scsh);
    float* scshf  = (float*)(ws + off_scshf);
    float* gapb   = (float*)(ws + off_gap);
    float* pfin   = (float*)(ws + off_pfin);

    // 1. zero accumulators (offmod + ypre + outpre contiguous)
    k_zero<<<2048, 256, 0, stream>>>((float4*)(ws + off_offmod), 720896);
    // 2. transpose x -> NHWC f16
    k_xpose<<<dim3(16, 32, 2), 256, 0, stream>>>(x, xT);
    // 3. weight conversions (coalesced LDS transposes)
    k_convw1<<<2048, 256, 0, stream>>>(w1, A1);
    k_convw9<<<dim3(256, 4, 3), 256, 0, stream>>>(w2, w3, w4, A2, A3, A4);
    k_convoff<<<dim3(128, 4), 256, 0, stream>>>(woff1, wm1, woff2, wm2, woff3, wm3, woff4, wm4, Aoff);
    k_afuse<<<1280, 256, 0, stream>>>(wfuse, Afuse);
    k_shtab<<<72, 256, 0, stream>>>(dtab0);
    // 4. offset/mod conv GEMM
    k_ogemm<<<dim3(16, 1, 18), 256, 0, stream>>>(Aoff, dtab0, xT, offmod);
    // 5. sampling tables
    k_sample<<<224, 256, 0, stream>>>(offmod, dtab);
    // 6. merged 4-branch deform GEMM (256x128 tiles)
    k_dgemm<<<dim3(16, 1, 56), 512, 0, stream>>>(Aall, dtab, xT, ypre);
    // 7. branch BN stats
    k_bnstats<<<dim3(256, 4), 256, 0, stream>>>(ypre, ypre + 524288, ypre + 2 * 524288, ypre + 3 * 524288,
                                                g1, g2, g3, g4, b1, b2, b3, b4, scsh);
    // 8. pool branch
    k_gap<<<4096, 256, 0, stream>>>(x, gapb);
    k_pool<<<256, 256, 0, stream>>>(gapb, wpool, gp, bp, pfin);
    // 9. concat (BN+relu applied) as f16 [2048][1280], coalesced transpose
    k_xcat<<<dim3(32, 20), 256, 0, stream>>>(ypre, scsh, pfin, xcat);
    // 10. fuse GEMM
    k_fgemm<<<dim3(16, 2, 8), 256, 0, stream>>>(Afuse, xcat, outpre);
    // 11. final BN stats + apply
    k_bnstats<<<dim3(256, 1), 256, 0, stream>>>(outpre, outpre, outpre, outpre,
                                                gf, gf, gf, gf, bf, bf, bf, bf, scshf);
    k_final<<<2048, 256, 0, stream>>>(outpre, scshf, (float*)d_out);
}

// Round 4
// 412.030 us; speedup vs baseline: 3.2288x; 1.0387x over previous
//
#include <hip/hip_runtime.h>
#include <hip/hip_fp16.h>
#include <cstdint>
#include <cstddef>

#define EPSV 1e-5f

typedef _Float16 f16x8 __attribute__((ext_vector_type(8)));
typedef float f32x4 __attribute__((ext_vector_type(4)));

__device__ __forceinline__ short f2h(float f) {
    _Float16 h = (_Float16)f;
    union { _Float16 h; short s; } u; u.h = h; return u.s;
}
__device__ __forceinline__ __half2 u2h2(unsigned u) {
    union { unsigned u; __half2 h; } x; x.u = u; return x.h;
}
__device__ __forceinline__ unsigned packh2(float w) {
    _Float16 h = (_Float16)w;
    union { _Float16 h; unsigned short s; } u; u.h = h;
    return (unsigned)u.s * 0x10001u;
}

// ---------------- zero init ----------------
__global__ void k_zero(float4* p, int n4) {
    int i = blockIdx.x * blockDim.x + threadIdx.x;
    int stride = gridDim.x * blockDim.x;
    for (; i < n4; i += stride) p[i] = float4{0.f, 0.f, 0.f, 0.f};
}

// ---------------- transpose x: [B][C][HW] f32 -> xT [B][HW][C] f16 ----------------
__global__ void k_xpose(const float* __restrict__ x, short* __restrict__ xT) {
    int hw0 = blockIdx.x * 64, c0 = blockIdx.y * 64, b = blockIdx.z;
    __shared__ short tile[64][72];
    int t = threadIdx.x;
    const float* xb = x + (size_t)b * 2048 * 1024;
    int hwi = t & 63, cr = t >> 6;
    #pragma unroll
    for (int r = 0; r < 16; r++) {
        int cl = cr + r * 4;
        tile[hwi][cl] = f2h(xb[(size_t)(c0 + cl) * 1024 + hw0 + hwi]);
    }
    __syncthreads();
    short* xTb = xT + (size_t)b * 1024 * 2048;
    int ci = t & 63, hr = t >> 6;
    #pragma unroll
    for (int r = 0; r < 16; r++) {
        int hwr = hr + r * 4;
        xTb[(size_t)(hw0 + hwr) * 2048 + c0 + ci] = tile[hwr][ci];
    }
}

// ---------------- misc prep: w1 convert | wfuse convert | synthetic 1-tap table ----------------
__global__ void k_misc(const float* __restrict__ w1, short* __restrict__ A1,
                       const float* __restrict__ wfuse, short* __restrict__ Af,
                       int* __restrict__ dtab0) {
    int bx = blockIdx.x;
    int t = threadIdx.x;
    if (bx < 2048) {
        int i = bx * 256 + t;
        A1[i] = f2h(w1[i]);
    } else if (bx < 3328) {
        int i = (bx - 2048) * 256 + t;
        Af[i] = f2h(wfuse[i]);
    } else {
        int i = (bx - 3328) * 256 + t;   // 9*2048
        if (i >= 9 * 2048) return;
        int j = i >> 11, p = i & 2047;
        int hw = p & 1023, h = hw >> 5, w = hw & 31;
        int y = h + j / 3 - 1, xx = w + j % 3 - 1;
        bool v = (y >= 0 && y < 32 && xx >= 0 && xx < 32);
        int4 ii = {v ? y * 32 + xx : 0, 0, 0, 0};
        uint4 ww = {v ? packh2(1.f) : 0u, 0u, 0u, 0u};
        ((int4*)dtab0)[(size_t)i * 2] = ii;
        ((uint4*)dtab0)[(size_t)i * 2 + 1] = ww;
    }
}

// ---------------- 3x3 branch weights: [o][c][9] f32 -> [o][j*2048+c] f16, LDS transpose ----------------
__global__ void k_convw9(const float* w2, const float* w3, const float* w4,
                         short* A2, short* A3, short* A4) {
    int o = blockIdx.x, cch = blockIdx.y, br = blockIdx.z;
    const float* src = br == 0 ? w2 : br == 1 ? w3 : w4;
    short* dst = br == 0 ? A2 : br == 1 ? A3 : A4;
    __shared__ short lds[4608];
    int t = threadIdx.x;
    const float* basep = src + ((size_t)o * 2048 + cch * 512) * 9;
    #pragma unroll
    for (int s = 0; s < 18; s++) {
        int idx = s * 256 + t;
        int c = idx / 9, jj = idx - c * 9;
        lds[jj * 512 + c] = f2h(basep[idx]);
    }
    __syncthreads();
    short* dbase = dst + (size_t)o * 18432 + cch * 512;
    #pragma unroll
    for (int s = 0; s < 18; s++) {
        int idx = s * 256 + t;
        int jj = idx >> 9, c = idx & 511;
        dbase[(size_t)jj * 2048 + c] = lds[idx];
    }
}

// ---------------- offset/mod weights -> Aoff[128][j*2048+c] f16, LDS transpose ----------------
__global__ void k_convoff(const float* woff1, const float* wm1, const float* woff2, const float* wm2,
                          const float* woff3, const float* wm3, const float* woff4, const float* wm4,
                          short* Aoff) {
    int ch = blockIdx.x, cch = blockIdx.y;
    int t = threadIdx.x;
    short* dbase = Aoff + (size_t)ch * 18432 + cch * 512;
    if (ch >= 84) {
        #pragma unroll
        for (int s = 0; s < 18; s++) {
            int idx = s * 256 + t;
            int jj = idx >> 9, c = idx & 511;
            dbase[(size_t)jj * 2048 + c] = 0;
        }
        return;
    }
    const float* src; int oc;
    if (ch < 2)       { src = woff1; oc = ch; }
    else if (ch == 2) { src = wm1;   oc = 0; }
    else if (ch < 21) { src = woff2; oc = ch - 3; }
    else if (ch < 30) { src = wm2;   oc = ch - 21; }
    else if (ch < 48) { src = woff3; oc = ch - 30; }
    else if (ch < 57) { src = wm3;   oc = ch - 48; }
    else if (ch < 75) { src = woff4; oc = ch - 57; }
    else              { src = wm4;   oc = ch - 75; }
    __shared__ short lds[4608];
    const float* basep = src + ((size_t)oc * 2048 + cch * 512) * 9;
    #pragma unroll
    for (int s = 0; s < 18; s++) {
        int idx = s * 256 + t;
        int c = idx / 9, jj = idx - c * 9;
        lds[jj * 512 + c] = f2h(basep[idx]);
    }
    __syncthreads();
    #pragma unroll
    for (int s = 0; s < 18; s++) {
        int idx = s * 256 + t;
        int jj = idx >> 9, c = idx & 511;
        dbase[(size_t)jj * 2048 + c] = lds[idx];
    }
}

// ---------------- deform sampling tables (ii + packed-f16 tap weights) ----------------
__global__ void k_sample(const float* OM, int* dtabi) {
    int i = blockIdx.x * 256 + threadIdx.x;
    if (i >= 57344) return;
    int br, j, p;
    if (i < 2048) { br = 0; j = 0; p = i; }
    else { int r = i - 2048; br = 1 + r / 18432; r %= 18432; j = r >> 11; p = r & 2047; }
    const int dil_[4] = {1, 6, 12, 18};
    const int pad_[4] = {0, 6, 12, 18};
    const int cho_[4] = {0, 3, 30, 57};
    const int chm_[4] = {2, 21, 48, 75};
    const int tbo_[4] = {0, 2048, 20480, 38912};
    int J = br ? 9 : 1;
    int dil = dil_[br], pad = pad_[br];
    int hw = p & 1023, h = hw >> 5, w = hw & 31;
    float offy = OM[(size_t)(cho_[br] + j) * 2048 + p];
    float offx = OM[(size_t)(cho_[br] + J + j) * 2048 + p];
    float mz   = OM[(size_t)(chm_[br] + j) * 2048 + p];
    float m = 1.f / (1.f + expf(-mz));
    int ky = j / 3, kx = j - ky * 3;
    float fh = (float)(h + ky * dil) + offy;
    float fw = (float)(w + kx * dil) + offx;
    int limi = 31 + 2 * pad;
    float lim = (float)limi;
    fh = fminf(fmaxf(fh, 0.f), lim);
    fw = fminf(fmaxf(fw, 0.f), lim);
    float y0f = floorf(fh), x0f = floorf(fw);
    float wy = fh - y0f, wx = fw - x0f;
    int y0 = (int)y0f, x0 = (int)x0f;
    int y1 = min(y0 + 1, limi), x1 = min(x0 + 1, limi);
    int4 ii; uint4 ww;
    {
        int yo = y0 - pad, xo = x0 - pad;
        bool v = ((unsigned)yo < 32u) && ((unsigned)xo < 32u);
        ii.x = v ? yo * 32 + xo : 0; ww.x = v ? packh2((1.f - wy) * (1.f - wx) * m) : 0u;
    }
    {
        int yo = y0 - pad, xo = x1 - pad;
        bool v = ((unsigned)yo < 32u) && ((unsigned)xo < 32u);
        ii.y = v ? yo * 32 + xo : 0; ww.y = v ? packh2((1.f - wy) * wx * m) : 0u;
    }
    {
        int yo = y1 - pad, xo = x0 - pad;
        bool v = ((unsigned)yo < 32u) && ((unsigned)xo < 32u);
        ii.z = v ? yo * 32 + xo : 0; ww.z = v ? packh2(wy * (1.f - wx) * m) : 0u;
    }
    {
        int yo = y1 - pad, xo = x1 - pad;
        bool v = ((unsigned)yo < 32u) && ((unsigned)xo < 32u);
        ii.w = v ? yo * 32 + xo : 0; ww.w = v ? packh2(wy * wx * m) : 0u;
    }
    int ent = tbo_[br] + j * 2048 + p;
    ((int4*)dtabi)[(size_t)ent * 2] = ii;
    ((uint4*)dtabi)[(size_t)ent * 2 + 1] = ww;
}

// ---------------- pipelined gather GEMM: (WM*64)x128 tile, BK=32, 16x16x32 f16 ----------------
// Register-prefetch of next K-step's A + gather loads; they fly during ds_read+MFMA.
template <int WM>
__device__ __forceinline__ void gemm_gather_f16(
    const short* __restrict__ A, const int* __restrict__ tab,
    const short* __restrict__ xT, float* __restrict__ C,
    int K, int kbeg, int kend, int nbase)
{
    constexpr int TPB = WM * 128;       // threads
    constexpr int TPP = TPB / 128;      // threads per position
    constexpr int CPT = 32 / TPP;       // channels per thread (8 or 16)
    constexpr int NG = CPT / 8;         // uint4 groups per tap
    __shared__ __align__(16) short At[WM * 64][40];
    __shared__ __align__(16) short Bt[128][40];
    int t = threadIdx.x;
    f32x4 acc[4][4] = {};

    int p = t / TPP;
    int q = (t % TPP) * CPT;
    int pg = nbase + p;
    int bb = nbase >> 10;
    int jj = kbeg >> 11;
    const int4* te = (const int4*)tab + ((size_t)jj * 2048 + pg) * 2;
    int4 ii = te[0];
    uint4 wp = *(const uint4*)(te + 1);
    __half2 wt0 = u2h2(wp.x), wt1 = u2h2(wp.y), wt2 = u2h2(wp.z), wt3 = u2h2(wp.w);
    const short* xbase = xT + (size_t)bb * 1024 * 2048 + q;
    const short* rp0 = xbase + (size_t)ii.x * 2048;
    const short* rp1 = xbase + (size_t)ii.y * 2048;
    const short* rp2 = xbase + (size_t)ii.z * 2048;
    const short* rp3 = xbase + (size_t)ii.w * 2048;

    int arow = t >> 1;
    int aseg = (t & 1) * 16;
    const short* Ar = A + (size_t)arow * K + aseg;

    int lane = t & 63, wv = t >> 6;
    int mq = (wv >> 1) * 64, nq = (wv & 1) * 64;
    int lm = lane & 15, quad = lane >> 4;

    // prologue loads for k = kbeg
    uint4 a0 = *(const uint4*)(Ar + kbeg);
    uint4 a1 = *(const uint4*)(Ar + kbeg + 8);
    uint4 G0[NG], G1[NG], G2[NG], G3[NG];
    {
        int ck = kbeg & 2047;
        #pragma unroll
        for (int g = 0; g < NG; g++) {
            int o8 = ck + g * 8;
            G0[g] = *(const uint4*)(rp0 + o8);
            G1[g] = *(const uint4*)(rp1 + o8);
            G2[g] = *(const uint4*)(rp2 + o8);
            G3[g] = *(const uint4*)(rp3 + o8);
        }
    }

    for (int k0 = kbeg; k0 < kend; k0 += 32) {
        // combine current gather in regs (VALU only)
        uint4 pk[NG];
        #pragma unroll
        for (int g = 0; g < NG; g++) {
            __half2 r0 = __hmul2(u2h2(G0[g].x), wt0);
            __half2 r1 = __hmul2(u2h2(G0[g].y), wt0);
            __half2 r2 = __hmul2(u2h2(G0[g].z), wt0);
            __half2 r3 = __hmul2(u2h2(G0[g].w), wt0);
            r0 = __hfma2(u2h2(G1[g].x), wt1, r0);
            r1 = __hfma2(u2h2(G1[g].y), wt1, r1);
            r2 = __hfma2(u2h2(G1[g].z), wt1, r2);
            r3 = __hfma2(u2h2(G1[g].w), wt1, r3);
            r0 = __hfma2(u2h2(G2[g].x), wt2, r0);
            r1 = __hfma2(u2h2(G2[g].y), wt2, r1);
            r2 = __hfma2(u2h2(G2[g].z), wt2, r2);
            r3 = __hfma2(u2h2(G2[g].w), wt2, r3);
            r0 = __hfma2(u2h2(G3[g].x), wt3, r0);
            r1 = __hfma2(u2h2(G3[g].y), wt3, r1);
            r2 = __hfma2(u2h2(G3[g].z), wt3, r2);
            r3 = __hfma2(u2h2(G3[g].w), wt3, r3);
            union { __half2 h[4]; uint4 u; } u;
            u.h[0] = r0; u.h[1] = r1; u.h[2] = r2; u.h[3] = r3;
            pk[g] = u.u;
        }
        __syncthreads();   // previous iteration's ds_reads complete
        *(uint4*)&At[arow][aseg]     = a0;
        *(uint4*)&At[arow][aseg + 8] = a1;
        #pragma unroll
        for (int g = 0; g < NG; g++) *(uint4*)&Bt[p][q + g * 8] = pk[g];
        // issue next-step loads (in flight across the MFMA phase)
        {
            int kn = (k0 + 32 < kend) ? k0 + 32 : k0;
            int cn = kn & 2047;
            a0 = *(const uint4*)(Ar + kn);
            a1 = *(const uint4*)(Ar + kn + 8);
            #pragma unroll
            for (int g = 0; g < NG; g++) {
                int o8 = cn + g * 8;
                G0[g] = *(const uint4*)(rp0 + o8);
                G1[g] = *(const uint4*)(rp1 + o8);
                G2[g] = *(const uint4*)(rp2 + o8);
                G3[g] = *(const uint4*)(rp3 + o8);
            }
        }
        __syncthreads();   // LDS tiles ready
        f16x8 af[4], bfv[4];
        #pragma unroll
        for (int f = 0; f < 4; f++) {
            af[f]  = *(const f16x8*)&At[mq + f * 16 + lm][quad * 8];
            bfv[f] = *(const f16x8*)&Bt[nq + f * 16 + lm][quad * 8];
        }
        #pragma unroll
        for (int fm = 0; fm < 4; fm++)
            #pragma unroll
            for (int fn = 0; fn < 4; fn++)
                acc[fm][fn] = __builtin_amdgcn_mfma_f32_16x16x32_f16(af[fm], bfv[fn], acc[fm][fn], 0, 0, 0);
    }
    #pragma unroll
    for (int fm = 0; fm < 4; fm++) {
        int row0 = mq + fm * 16 + quad * 4;
        #pragma unroll
        for (int fn = 0; fn < 4; fn++) {
            int col = nbase + nq + fn * 16 + lm;
            #pragma unroll
            for (int r = 0; r < 4; r++)
                atomicAdd(&C[(size_t)(row0 + r) * 2048 + col], acc[fm][fn][r]);
        }
    }
}

// offset/mod conv GEMM: M=128, K=18432, kchunk=512, grid (16,1,36), block 256
__global__ __launch_bounds__(256, 3) void k_ogemm(const short* __restrict__ Aoff,
                                                  const int* __restrict__ dtab0,
                                                  const short* __restrict__ xT,
                                                  float* __restrict__ offmod) {
    int kbeg = blockIdx.z * 512;
    gemm_gather_f16<2>(Aoff, dtab0, xT, offmod, 18432, kbeg, kbeg + 512, blockIdx.x * 128);
}

// merged 4-branch deform GEMM: M=256, kchunk=1024, grid (16,1,56), block 512
__global__ __launch_bounds__(512, 4) void k_dgemm(const short* __restrict__ Aall,
                                                  const int* __restrict__ dtab,
                                                  const short* __restrict__ xT,
                                                  float* __restrict__ ypre) {
    int z = blockIdx.z;
    int br, kbeg;
    if (z < 2) { br = 0; kbeg = z * 1024; }
    else { int zz = z - 2; br = 1 + zz / 18; kbeg = (zz % 18) * 1024; }
    const size_t aoffs[4] = {0, 524288, 524288 + 4718592, 524288 + 2 * (size_t)4718592};
    const int tbo[4] = {0, 2048, 20480, 38912};
    int K = br ? 18432 : 2048;
    gemm_gather_f16<4>(Aall + aoffs[br], dtab + (size_t)tbo[br] * 8, xT,
                       ypre + (size_t)br * 524288, K, kbeg, kbeg + 1024, blockIdx.x * 128);
}

// fuse GEMM: dense B [2048][1280] f16, M=256, K=1280, kchunk=160, grid (16,2,8)
__global__ __launch_bounds__(256) void k_fgemm(const short* __restrict__ A,
                                               const short* __restrict__ Bp,
                                               float* __restrict__ C) {
    __shared__ __align__(16) short At[128][40];
    __shared__ __align__(16) short Bt[128][40];
    int t = threadIdx.x;
    int nbase = blockIdx.x * 128, mbase = blockIdx.y * 128;
    int kbeg = blockIdx.z * 160, kend = kbeg + 160;
    const int K = 1280;
    f32x4 acc[4][4] = {};
    int lane = t & 63, wv = t >> 6;
    int mq = (wv >> 1) * 64, nq = (wv & 1) * 64;
    int lm = lane & 15, quad = lane >> 4;
    for (int k0 = kbeg; k0 < kend; k0 += 32) {
        int row = t >> 2, seg = t & 3;
        *(uint4*)&At[row][seg * 8] = *(const uint4*)(A + (size_t)(mbase + row) * K + k0 + seg * 8);
        *(uint4*)&At[row + 64][seg * 8] = *(const uint4*)(A + (size_t)(mbase + row + 64) * K + k0 + seg * 8);
        *(uint4*)&Bt[row][seg * 8] = *(const uint4*)(Bp + (size_t)(nbase + row) * K + k0 + seg * 8);
        *(uint4*)&Bt[row + 64][seg * 8] = *(const uint4*)(Bp + (size_t)(nbase + row + 64) * K + k0 + seg * 8);
        __syncthreads();
        f16x8 af[4], bfv[4];
        #pragma unroll
        for (int f = 0; f < 4; f++) {
            af[f]  = *(const f16x8*)&At[mq + f * 16 + lm][quad * 8];
            bfv[f] = *(const f16x8*)&Bt[nq + f * 16 + lm][quad * 8];
        }
        #pragma unroll
        for (int fm = 0; fm < 4; fm++)
            #pragma unroll
            for (int fn = 0; fn < 4; fn++)
                acc[fm][fn] = __builtin_amdgcn_mfma_f32_16x16x32_f16(af[fm], bfv[fn], acc[fm][fn], 0, 0, 0);
        __syncthreads();
    }
    #pragma unroll
    for (int fm = 0; fm < 4; fm++) {
        int row0 = mbase + mq + fm * 16 + quad * 4;
        #pragma unroll
        for (int fn = 0; fn < 4; fn++) {
            int col = nbase + nq + fn * 16 + lm;
            #pragma unroll
            for (int r = 0; r < 4; r++)
                atomicAdd(&C[(size_t)(row0 + r) * 2048 + col], acc[fm][fn][r]);
        }
    }
}

// ---------------- BN stats ----------------
__global__ void k_bnstats(const float* Y0, const float* Y1, const float* Y2, const float* Y3,
                          const float* g0, const float* g1, const float* g2, const float* g3,
                          const float* b0, const float* b1, const float* b2, const float* b3,
                          float* S) {
    int br = blockIdx.y;
    const float* Y = br == 0 ? Y0 : br == 1 ? Y1 : br == 2 ? Y2 : Y3;
    const float* g = br == 0 ? g0 : br == 1 ? g1 : br == 2 ? g2 : g3;
    const float* b = br == 0 ? b0 : br == 1 ? b1 : br == 2 ? b2 : b3;
    float* so = S + (size_t)br * 512;
    int o = blockIdx.x, t = threadIdx.x;
    const float* row = Y + (size_t)o * 2048;
    float s = 0.f, ss = 0.f;
    for (int i = t; i < 2048; i += 256) { float v = row[i]; s += v; ss += v * v; }
    #pragma unroll
    for (int off = 32; off; off >>= 1) { s += __shfl_down(s, off); ss += __shfl_down(ss, off); }
    __shared__ float ls[4], lss[4];
    int wv = t >> 6;
    if ((t & 63) == 0) { ls[wv] = s; lss[wv] = ss; }
    __syncthreads();
    if (t == 0) {
        s = ls[0] + ls[1] + ls[2] + ls[3];
        ss = lss[0] + lss[1] + lss[2] + lss[3];
        float mu = s * (1.f / 2048.f);
        float var = ss * (1.f / 2048.f) - mu * mu;
        float sc = g[o] * rsqrtf(var + EPSV);
        so[o] = sc;
        so[256 + o] = b[o] - mu * sc;
    }
}

// ---------------- global average pool ----------------
__global__ void k_gap(const float* X, float* gap) {
    int bc = blockIdx.x;
    const float* row = X + (size_t)bc * 1024;
    int t = threadIdx.x;
    float s = row[t] + row[t + 256] + row[t + 512] + row[t + 768];
    #pragma unroll
    for (int off = 32; off; off >>= 1) s += __shfl_down(s, off);
    __shared__ float ls[4];
    if ((t & 63) == 0) ls[t >> 6] = s;
    __syncthreads();
    if (t == 0) gap[bc] = (ls[0] + ls[1] + ls[2] + ls[3]) * (1.f / 1024.f);
}

// ---------------- pool 1x1 conv + BN over batch + relu ----------------
__global__ void k_pool(const float* gap, const float* wpool, const float* gp, const float* bp,
                       float* pfin) {
    int o = blockIdx.x, t = threadIdx.x;
    float s0 = 0.f, s1 = 0.f;
    const float* wr = wpool + (size_t)o * 2048;
    for (int c = t; c < 2048; c += 256) {
        float wv = wr[c];
        s0 += wv * gap[c];
        s1 += wv * gap[2048 + c];
    }
    #pragma unroll
    for (int off = 32; off; off >>= 1) { s0 += __shfl_down(s0, off); s1 += __shfl_down(s1, off); }
    __shared__ float l0[4], l1[4];
    int wv_ = t >> 6;
    if ((t & 63) == 0) { l0[wv_] = s0; l1[wv_] = s1; }
    __syncthreads();
    if (t == 0) {
        float p0 = l0[0] + l0[1] + l0[2] + l0[3];
        float p1 = l1[0] + l1[1] + l1[2] + l1[3];
        float mu = 0.5f * (p0 + p1);
        float d0 = p0 - mu, d1 = p1 - mu;
        float var = 0.5f * (d0 * d0 + d1 * d1);
        float r = rsqrtf(var + EPSV);
        pfin[o]       = fmaxf(d0 * r * gp[o] + bp[o], 0.f);
        pfin[256 + o] = fmaxf(d1 * r * gp[o] + bp[o], 0.f);
    }
}

// ---------------- xcat transpose: ypre[1024ch][2048p] (BN+relu) + pfin -> xcat[p][1280] f16 ----------------
__global__ void k_xcat(const float* __restrict__ ypre, const float* __restrict__ S,
                       const float* __restrict__ pfin, short* __restrict__ xcat) {
    int p0 = blockIdx.x * 64, ct = blockIdx.y;
    int t = threadIdx.x;
    if (ct >= 16) {
        int c0 = 1024 + (ct - 16) * 64;
        int ci = t & 63, pr = t >> 6;
        #pragma unroll
        for (int r = 0; r < 16; r++) {
            int pw = p0 + pr + r * 4;
            int b = pw >> 10;
            xcat[(size_t)pw * 1280 + c0 + ci] = f2h(pfin[b * 256 + (c0 - 1024) + ci]);
        }
        return;
    }
    __shared__ short tile[64][72];
    int c0 = ct * 64;
    int pi = t & 63, cr = t >> 6;
    #pragma unroll
    for (int r = 0; r < 16; r++) {
        int cl = cr + r * 4;
        int cg = c0 + cl;
        int br = cg >> 8, cc = cg & 255;
        float sc = S[br * 512 + cc], sh = S[br * 512 + 256 + cc];
        float v = fmaxf(ypre[(size_t)cg * 2048 + p0 + pi] * sc + sh, 0.f);
        tile[pi][cl] = f2h(v);
    }
    __syncthreads();
    int ci = t & 63, pr = t >> 6;
    #pragma unroll
    for (int r = 0; r < 16; r++) {
        int pw = pr + r * 4;
        xcat[(size_t)(p0 + pw) * 1280 + c0 + ci] = tile[pw][ci];
    }
}

// ---------------- final BN + relu + layout to [B][O][HW] ----------------
__global__ void k_final(const float* outpre, const float* S, float* dout) {
    int i = blockIdx.x * 256 + threadIdx.x;    // 524288
    int hw = i & 1023, o = (i >> 10) & 255, b = i >> 18;
    float v = outpre[(size_t)o * 2048 + b * 1024 + hw] * S[o] + S[256 + o];
    dout[i] = fmaxf(v, 0.f);
}

extern "C" void kernel_launch(void* const* d_in, const int* in_sizes, int n_in,
                              void* d_out, int out_size, void* d_ws, size_t ws_size,
                              hipStream_t stream) {
    const float* x     = (const float*)d_in[0];
    const float* woff1 = (const float*)d_in[1];
    const float* wm1   = (const float*)d_in[2];
    const float* w1    = (const float*)d_in[3];
    const float* g1    = (const float*)d_in[4];
    const float* b1    = (const float*)d_in[5];
    const float* woff2 = (const float*)d_in[6];
    const float* wm2   = (const float*)d_in[7];
    const float* w2    = (const float*)d_in[8];
    const float* g2    = (const float*)d_in[9];
    const float* b2    = (const float*)d_in[10];
    const float* woff3 = (const float*)d_in[11];
    const float* wm3   = (const float*)d_in[12];
    const float* w3    = (const float*)d_in[13];
    const float* g3    = (const float*)d_in[14];
    const float* b3    = (const float*)d_in[15];
    const float* woff4 = (const float*)d_in[16];
    const float* wm4   = (const float*)d_in[17];
    const float* w4    = (const float*)d_in[18];
    const float* g4    = (const float*)d_in[19];
    const float* b4    = (const float*)d_in[20];
    const float* wpool = (const float*)d_in[21];
    const float* gp    = (const float*)d_in[22];
    const float* bp    = (const float*)d_in[23];
    const float* wfuse = (const float*)d_in[24];
    const float* gf    = (const float*)d_in[25];
    const float* bf    = (const float*)d_in[26];

    char* ws = (char*)d_ws;
    size_t off = 0;
    auto alloc = [&](size_t bytes) {
        off = (off + 255) & ~(size_t)255;
        size_t o = off; off += bytes; return o;
    };
    // zero-init region contiguous: offmod | ypre | outpre
    size_t off_offmod = alloc(128 * 2048 * 4);
    size_t off_ypre   = alloc((size_t)4 * 256 * 2048 * 4);
    size_t off_outpre = alloc(256 * 2048 * 4);
    // A1..A4 contiguous (Aall)
    size_t off_A1     = alloc((size_t)256 * 2048 * 2);
    size_t off_A2     = alloc((size_t)256 * 18432 * 2);
    size_t off_A3     = alloc((size_t)256 * 18432 * 2);
    size_t off_A4     = alloc((size_t)256 * 18432 * 2);
    size_t off_Aoff   = alloc((size_t)128 * 18432 * 2);
    size_t off_Afuse  = alloc((size_t)256 * 1280 * 2);
    size_t off_xcat   = alloc((size_t)2048 * 1280 * 2);
    size_t off_xT     = alloc((size_t)2 * 1024 * 2048 * 2);
    size_t off_dtab0  = alloc((size_t)9 * 2048 * 32);
    size_t off_dtab   = alloc((size_t)57344 * 32);
    size_t off_scsh   = alloc((size_t)4 * 512 * 4);
    size_t off_scshf  = alloc((size_t)512 * 4);
    size_t off_gap    = alloc((size_t)4096 * 4);
    size_t off_pfin   = alloc((size_t)512 * 4);
    (void)ws_size; (void)in_sizes; (void)n_in; (void)out_size;

    float* offmod = (float*)(ws + off_offmod);
    float* ypre   = (float*)(ws + off_ypre);
    float* outpre = (float*)(ws + off_outpre);
    short* Aall   = (short*)(ws + off_A1);
    short* A1     = (short*)(ws + off_A1);
    short* A2     = (short*)(ws + off_A2);
    short* A3     = (short*)(ws + off_A3);
    short* A4     = (short*)(ws + off_A4);
    short* Aoff   = (short*)(ws + off_Aoff);
    short* Afuse  = (short*)(ws + off_Afuse);
    short* xcat   = (short*)(ws + off_xcat);
    short* xT     = (short*)(ws + off_xT);
    int*   dtab0  = (int*)(ws + off_dtab0);
    int*   dtab   = (int*)(ws + off_dtab);
    float* scsh   = (float*)(ws + off_scsh);
    float* scshf  = (float*)(ws + off_scshf);
    float* gapb   = (float*)(ws + off_gap);
    float* pfin   = (float*)(ws + off_pfin);

    // 1. zero accumulators (offmod + ypre + outpre contiguous)
    k_zero<<<2048, 256, 0, stream>>>((float4*)(ws + off_offmod), 720896);
    // 2. transpose x -> NHWC f16
    k_xpose<<<dim3(16, 32, 2), 256, 0, stream>>>(x, xT);
    // 3. weight conversions (coalesced LDS transposes) + misc prep
    k_misc<<<3400, 256, 0, stream>>>(w1, A1, wfuse, Afuse, dtab0);
    k_convw9<<<dim3(256, 4, 3), 256, 0, stream>>>(w2, w3, w4, A2, A3, A4);
    k_convoff<<<dim3(128, 4), 256, 0, stream>>>(woff1, wm1, woff2, wm2, woff3, wm3, woff4, wm4, Aoff);
    // 4. offset/mod conv GEMM (pipelined)
    k_ogemm<<<dim3(16, 1, 36), 256, 0, stream>>>(Aoff, dtab0, xT, offmod);
    // 5. sampling tables
    k_sample<<<224, 256, 0, stream>>>(offmod, dtab);
    // 6. merged 4-branch deform GEMM (256x128 tiles, pipelined)
    k_dgemm<<<dim3(16, 1, 56), 512, 0, stream>>>(Aall, dtab, xT, ypre);
    // 7. branch BN stats
    k_bnstats<<<dim3(256, 4), 256, 0, stream>>>(ypre, ypre + 524288, ypre + 2 * 524288, ypre + 3 * 524288,
                                                g1, g2, g3, g4, b1, b2, b3, b4, scsh);
    // 8. pool branch
    k_gap<<<4096, 256, 0, stream>>>(x, gapb);
    k_pool<<<256, 256, 0, stream>>>(gapb, wpool, gp, bp, pfin);
    // 9. concat (BN+relu applied) as f16 [2048][1280], coalesced transpose
    k_xcat<<<dim3(32, 20), 256, 0, stream>>>(ypre, scsh, pfin, xcat);
    // 10. fuse GEMM
    k_fgemm<<<dim3(16, 2, 8), 256, 0, stream>>>(Afuse, xcat, outpre);
    // 11. final BN stats + apply
    k_bnstats<<<dim3(256, 1), 256, 0, stream>>>(outpre, outpre, outpre, outpre,
                                                gf, gf, gf, gf, bf, bf, bf, bf, scshf);
    k_final<<<2048, 256, 0, stream>>>(outpre, scshf, (float*)d_out);
}